// Round 12
// baseline (372.518 us; speedup 1.0000x reference)
//
#include <hip/hip_runtime.h>
#include <hip/hip_fp16.h>
#include <math.h>

#define N_NODES 50000
#define N_EDGES 1600000
#define N_GRAPH 500
#define CHUNKS 128
#define EPC (N_EDGES / CHUNKS)  // 12500 edges per chunk
#define NP1 (N_NODES + 1)
#define NIT ((EPC + 1023) / 1024)  // 13 edge-iterations per histsort thread
#define GEMM_BLOCKS 128

// ---------- helpers ----------
__device__ __forceinline__ float rl(float v, int k) {
    return __int_as_float(__builtin_amdgcn_readlane(__float_as_int(v), k));
}
// accumulate 8 fp16 (uint4) into two float4
__device__ __forceinline__ void hacc16(float4& A, float4& B, uint4 w) {
    float2 f0 = __half22float2(*reinterpret_cast<__half2*>(&w.x));
    float2 f1 = __half22float2(*reinterpret_cast<__half2*>(&w.y));
    float2 f2 = __half22float2(*reinterpret_cast<__half2*>(&w.z));
    float2 f3 = __half22float2(*reinterpret_cast<__half2*>(&w.w));
    A.x += f0.x; A.y += f0.y; A.z += f1.x; A.w += f1.y;
    B.x += f2.x; B.y += f2.y; B.z += f3.x; B.w += f3.y;
}

// ---------- merged: blocks [0,CHUNKS) = histsort; [CHUNKS, CHUNKS+GEMM_BLOCKS) = gemm0
// histsort: per-chunk LDS histogram -> in-LDS scan -> chunk-local dst-sorted scatter.
// gemm0: y0 = x @ W1_0 (fp32 math, fp16 store), W1 first half in regs, second in LDS.
__global__ __launch_bounds__(1024) void hist_gemm0_kernel(const int* __restrict__ src,
                                                          const int* __restrict__ dst,
                                                          int* __restrict__ csrc_chunk,
                                                          unsigned short* __restrict__ locs,
                                                          const float* __restrict__ x,
                                                          const float* __restrict__ W1,
                                                          __half* __restrict__ y0, int N) {
    __shared__ unsigned packed[N_NODES / 2];  // 100 KB
    __shared__ unsigned aux[1024];
    const int tid = threadIdx.x;

    if (blockIdx.x < CHUNKS) {
        // ---- histsort path ----
        const int c = blockIdx.x;
        const int s0 = c * EPC;

        for (int i = tid; i < N_NODES / 2; i += 1024) packed[i] = 0;
        __syncthreads();

        unsigned short lrv[NIT];
#pragma unroll
        for (int it = 0; it < NIT; it++) {
            int e = s0 + it * 1024 + tid;
            if (e < s0 + EPC) {
                int d = dst[e];
                int sh = (d & 1) * 16;
                unsigned old = atomicAdd(&packed[d >> 1], 1u << sh);
                lrv[it] = (unsigned short)((old >> sh) & 0xffffu);
            }
        }
        __syncthreads();

        const int W = 25;
        int w0 = tid * W;
        int w1 = min(w0 + W, N_NODES / 2);
        unsigned run = 0;
        for (int i = w0; i < w1; i++) {
            unsigned v = packed[i];
            unsigned lo = v & 0xffffu, hi = v >> 16;
            packed[i] = run | ((run + lo) << 16);
            run += lo + hi;
        }
        aux[tid] = run;
        __syncthreads();
        for (int off = 1; off < 1024; off <<= 1) {
            unsigned t = (tid >= off) ? aux[tid - off] : 0;
            __syncthreads();
            aux[tid] += t;
            __syncthreads();
        }
        unsigned b0 = (tid == 0) ? 0 : aux[tid - 1];
        if (b0) {
            unsigned addv = b0 | (b0 << 16);
            for (int i = w0; i < w1; i++) packed[i] += addv;
        }
        __syncthreads();

        int* outc = csrc_chunk + (size_t)c * EPC;
#pragma unroll
        for (int it = 0; it < NIT; it++) {
            int e = s0 + it * 1024 + tid;
            if (e < s0 + EPC) {
                int d = dst[e];
                unsigned pw = packed[d >> 1];
                unsigned loc = (d & 1) ? (pw >> 16) : (pw & 0xffffu);
                outc[loc + lrv[it]] = src[e];
            }
        }
        unsigned short* lc = locs + (size_t)c * NP1;
        for (int d = tid; d <= N_NODES; d += 1024) {
            unsigned short loc;
            if (d == N_NODES) {
                loc = (unsigned short)EPC;
            } else {
                unsigned pw = packed[d >> 1];
                loc = (unsigned short)((d & 1) ? (pw >> 16) : (pw & 0xffffu));
            }
            lc[d] = loc;
        }
    } else {
        // ---- gemm0 path ----
        float* sW = (float*)packed;  // 64*64 floats = 16 KB (second K-half of W1)
        for (int i = tid; i < 64 * 64; i += 1024) sW[i] = W1[64 * 64 + i];
        __syncthreads();
        int lane = tid & 63;
        float w[64];
#pragma unroll
        for (int k = 0; k < 64; k++) w[k] = W1[k * 64 + lane];
        int wid = ((blockIdx.x - CHUNKS) * 1024 + tid) >> 6;
        const int totalWaves = GEMM_BLOCKS * 16;
        for (int node = wid; node < N; node += totalWaves) {
            float xa = x[(size_t)node * 128 + lane];
            float xb = x[(size_t)node * 128 + 64 + lane];
            float a0 = 0.f, a1 = 0.f, a2 = 0.f, a3 = 0.f;
#pragma unroll
            for (int k = 0; k < 64; k += 4) {
                a0 = fmaf(rl(xa, k + 0), w[k + 0], a0);
                a1 = fmaf(rl(xa, k + 1), w[k + 1], a1);
                a2 = fmaf(rl(xa, k + 2), w[k + 2], a2);
                a3 = fmaf(rl(xa, k + 3), w[k + 3], a3);
            }
#pragma unroll
            for (int k = 0; k < 64; k += 4) {
                a0 = fmaf(rl(xb, k + 0), sW[(k + 0) * 64 + lane], a0);
                a1 = fmaf(rl(xb, k + 1), sW[(k + 1) * 64 + lane], a1);
                a2 = fmaf(rl(xb, k + 2), sW[(k + 2) * 64 + lane], a2);
                a3 = fmaf(rl(xb, k + 3), sW[(k + 3) * 64 + lane], a3);
            }
            y0[(size_t)node * 64 + lane] = __float2half((a0 + a1) + (a2 + a3));
        }
    }
}

// ---------- base + scan1 fused ----------
__global__ __launch_bounds__(1024) void base_scan1_kernel(const unsigned short* __restrict__ locs,
                                                          unsigned short* __restrict__ base,
                                                          int* __restrict__ deg,
                                                          int* __restrict__ part, int N) {
    int d = blockIdx.x * 1024 + threadIdx.x;
    int run = 0;
    if (d < N) {
#pragma unroll 8
        for (int c = 0; c < CHUNKS; c++) {
            int l0 = locs[(size_t)c * NP1 + d];
            int l1 = locs[(size_t)c * NP1 + d + 1];
            base[(size_t)c * N + d] = (unsigned short)run;
            run += l1 - l0;
        }
        deg[d] = run;
    }
    int v = run;
#pragma unroll
    for (int o = 32; o >= 1; o >>= 1) v += __shfl_xor(v, o);
    __shared__ int red[16];
    if ((threadIdx.x & 63) == 0) red[threadIdx.x >> 6] = v;
    __syncthreads();
    if (threadIdx.x == 0) {
        int s = 0;
#pragma unroll
        for (int k = 0; k < 16; k++) s += red[k];
        part[blockIdx.x] = s;
    }
}

__global__ void scan2_kernel(int* __restrict__ part, int nb) {
    int lane = threadIdx.x;
    int v = (lane < nb) ? part[lane] : 0;
    int orig = v;
#pragma unroll
    for (int o = 1; o < 64; o <<= 1) {
        int t = __shfl_up(v, o);
        if (lane >= o) v += t;
    }
    if (lane < nb) part[lane] = v - orig;
    if (lane == nb - 1) part[nb] = v;
}

__global__ __launch_bounds__(1024) void scan3_kernel(const int* __restrict__ deg,
                                                     const int* __restrict__ part,
                                                     int* __restrict__ rowptr, int N) {
    int i = blockIdx.x * 1024 + threadIdx.x;
    int lane = threadIdx.x & 63;
    int w = threadIdx.x >> 6;
    int v = (i < N) ? deg[i] : 0;
    int inc = v;
#pragma unroll
    for (int o = 1; o < 64; o <<= 1) {
        int t = __shfl_up(inc, o);
        if (lane >= o) inc += t;
    }
    __shared__ int wsum[16];
    if (lane == 63) wsum[w] = inc;
    __syncthreads();
    if (threadIdx.x < 16) {
        int x = wsum[threadIdx.x];
        int xo = x;
#pragma unroll
        for (int o = 1; o < 16; o <<= 1) {
            int t = __shfl_up(x, o);
            if ((int)threadIdx.x >= o) x += t;
        }
        wsum[threadIdx.x] = x - xo;
    }
    __syncthreads();
    int b = part[blockIdx.x] + wsum[w];
    if (i < N) {
        rowptr[i] = b + inc - v;
        if (i == N - 1) rowptr[N] = b + inc;
    }
}

// ---------- gatherfill: one wave per node, lane covers 2 chunks ----------
__global__ __launch_bounds__(256) void gatherfill_kernel(const int* __restrict__ csrc_chunk,
                                                         const unsigned short* __restrict__ locs,
                                                         const unsigned short* __restrict__ base,
                                                         const int* __restrict__ rowptr,
                                                         int* __restrict__ csr_src) {
    const int perXcd = N_NODES / 8;  // 6250
    int xcd = blockIdx.x & 7;
    int idx = (blockIdx.x >> 3) * 4 + (threadIdx.x >> 6);
    if (idx >= perXcd) return;
    int wid = xcd * perXcd + idx;
    int lane = threadIdx.x & 63;
    int rp = rowptr[wid];
#pragma unroll
    for (int cc = 0; cc < 2; cc++) {
        int c = lane + cc * 64;
        const unsigned short* lc = locs + (size_t)c * NP1;
        int l0 = lc[wid];
        int l1 = lc[wid + 1];
        int cnt = l1 - l0;
        int ob = rp + (int)base[(size_t)c * N_NODES + wid];
        const int* in = csrc_chunk + (size_t)c * EPC + l0;
        for (int i = 0; i < cnt; i++) csr_src[ob + i] = in[i];
    }
}

// ---------- aggregation on fp16 y: uint4 loads, 8 edge slots, fp32 accum ----------
__global__ __launch_bounds__(256) void agg_kernel(const __half* __restrict__ yh,
                                                  const int* __restrict__ rowptr,
                                                  const int* __restrict__ csr_src,
                                                  float* __restrict__ u, int N) {
    int wid = (blockIdx.x * 256 + threadIdx.x) >> 6;
    int lane = threadIdx.x & 63;
    if (wid >= N) return;
    int q = lane >> 3;  // edge slot 0..7
    int r = lane & 7;   // feature oct 0..7 (8 halves = 16B each)
    int start = rowptr[wid];
    int end = rowptr[wid + 1];
    float4 A = make_float4(0.f, 0.f, 0.f, 0.f);
    float4 B = make_float4(0.f, 0.f, 0.f, 0.f);
    int j = start;
    for (; j + 64 <= end; j += 64) {
        int s0 = csr_src[j + q];
        int s1 = csr_src[j + 8 + q];
        int s2 = csr_src[j + 16 + q];
        int s3 = csr_src[j + 24 + q];
        int s4 = csr_src[j + 32 + q];
        int s5 = csr_src[j + 40 + q];
        int s6 = csr_src[j + 48 + q];
        int s7 = csr_src[j + 56 + q];
        uint4 w0 = *(const uint4*)(yh + (size_t)s0 * 64 + r * 8);
        uint4 w1 = *(const uint4*)(yh + (size_t)s1 * 64 + r * 8);
        uint4 w2 = *(const uint4*)(yh + (size_t)s2 * 64 + r * 8);
        uint4 w3 = *(const uint4*)(yh + (size_t)s3 * 64 + r * 8);
        uint4 w4 = *(const uint4*)(yh + (size_t)s4 * 64 + r * 8);
        uint4 w5 = *(const uint4*)(yh + (size_t)s5 * 64 + r * 8);
        uint4 w6 = *(const uint4*)(yh + (size_t)s6 * 64 + r * 8);
        uint4 w7 = *(const uint4*)(yh + (size_t)s7 * 64 + r * 8);
        hacc16(A, B, w0); hacc16(A, B, w1); hacc16(A, B, w2); hacc16(A, B, w3);
        hacc16(A, B, w4); hacc16(A, B, w5); hacc16(A, B, w6); hacc16(A, B, w7);
    }
    // tail: < 64 edges, 8 predicated independent groups of 8
#pragma unroll
    for (int m = 0; m < 8; m++) {
        int e = j + 8 * m + q;
        if (e < end) {
            int s = csr_src[e];
            uint4 w = *(const uint4*)(yh + (size_t)s * 64 + r * 8);
            hacc16(A, B, w);
        }
    }
    // reduce over 8 edge slots
#pragma unroll
    for (int o = 8; o <= 32; o <<= 1) {
        A.x += __shfl_xor(A.x, o); A.y += __shfl_xor(A.y, o);
        A.z += __shfl_xor(A.z, o); A.w += __shfl_xor(A.w, o);
        B.x += __shfl_xor(B.x, o); B.y += __shfl_xor(B.y, o);
        B.z += __shfl_xor(B.z, o); B.w += __shfl_xor(B.w, o);
    }
    if (lane < 8) {
        uint4 w = *(const uint4*)(yh + (size_t)wid * 64 + r * 8);
        hacc16(A, B, w);
        *(float4*)(u + (size_t)wid * 64 + r * 8) = A;
        *(float4*)(u + (size_t)wid * 64 + r * 8 + 4) = B;
    }
}

// ---------- fused mlpAB (layers 0,1): fp32 u in, fp16 ynext out ----------
template <int LAYER>
__global__ __launch_bounds__(256) void mlpAB_kernel(const float* __restrict__ u,
                                                    const float* __restrict__ b1,
                                                    const float* __restrict__ W2,
                                                    const float* __restrict__ b2,
                                                    const float* __restrict__ W1n,
                                                    const float* __restrict__ Wm,
                                                    __half* __restrict__ ynext,
                                                    float* __restrict__ score,
                                                    int N, int totalWaves) {
    int lane = threadIdx.x & 63;
    int wid = (blockIdx.x * 256 + threadIdx.x) >> 6;
    float w2[64], w1[64];
#pragma unroll
    for (int k = 0; k < 64; k++) w2[k] = W2[k * 64 + lane];
#pragma unroll
    for (int k = 0; k < 64; k++) w1[k] = W1n[k * 64 + lane];
    float bb1 = b1[lane], bb2 = b2[lane], wm = Wm[LAYER * 64 + lane];

    int node = wid;
    float uin = (node < N) ? u[(size_t)node * 64 + lane] : 0.f;
    for (; node < N; node += totalWaves) {
        int nn = node + totalWaves;
        float unext = (nn < N) ? u[(size_t)nn * 64 + lane] : 0.f;
        float t = fmaxf(uin + bb1, 0.f);
        float a0 = 0.f, a1 = 0.f, a2 = 0.f, a3 = 0.f;
#pragma unroll
        for (int k = 0; k < 64; k += 4) {
            a0 = fmaf(rl(t, k + 0), w2[k + 0], a0);
            a1 = fmaf(rl(t, k + 1), w2[k + 1], a1);
            a2 = fmaf(rl(t, k + 2), w2[k + 2], a2);
            a3 = fmaf(rl(t, k + 3), w2[k + 3], a3);
        }
        float h = fmaxf(bb2 + ((a0 + a1) + (a2 + a3)), 0.f);
        float p = h * wm;
#pragma unroll
        for (int o = 32; o >= 1; o >>= 1) p += __shfl_xor(p, o);
        if (lane == 0) {
            if (LAYER == 0) score[node] = p;
            else score[node] += p;
        }
        float y0 = 0.f, y1 = 0.f, y2 = 0.f, y3 = 0.f;
#pragma unroll
        for (int k = 0; k < 64; k += 4) {
            y0 = fmaf(rl(h, k + 0), w1[k + 0], y0);
            y1 = fmaf(rl(h, k + 1), w1[k + 1], y1);
            y2 = fmaf(rl(h, k + 2), w1[k + 2], y2);
            y3 = fmaf(rl(h, k + 3), w1[k + 3], y3);
        }
        ynext[(size_t)node * 64 + lane] = __float2half((y0 + y1) + (y2 + y3));
        uin = unext;
    }
}

// ---------- mlpA2 (layer 2) ----------
__global__ __launch_bounds__(256) void mlpA2_kernel(const float* __restrict__ u,
                                                    const float* __restrict__ b1,
                                                    const float* __restrict__ W2,
                                                    const float* __restrict__ b2,
                                                    const float* __restrict__ Wm,
                                                    float* __restrict__ score,
                                                    int N, int totalWaves) {
    int lane = threadIdx.x & 63;
    int wid = (blockIdx.x * 256 + threadIdx.x) >> 6;
    float w2[64];
#pragma unroll
    for (int k = 0; k < 64; k++) w2[k] = W2[k * 64 + lane];
    float bb1 = b1[lane], bb2 = b2[lane], wm = Wm[2 * 64 + lane];

    int node = wid;
    float uin = (node < N) ? u[(size_t)node * 64 + lane] : 0.f;
    for (; node < N; node += totalWaves) {
        int nn = node + totalWaves;
        float unext = (nn < N) ? u[(size_t)nn * 64 + lane] : 0.f;
        float t = fmaxf(uin + bb1, 0.f);
        float a0 = 0.f, a1 = 0.f, a2 = 0.f, a3 = 0.f;
#pragma unroll
        for (int k = 0; k < 64; k += 4) {
            a0 = fmaf(rl(t, k + 0), w2[k + 0], a0);
            a1 = fmaf(rl(t, k + 1), w2[k + 1], a1);
            a2 = fmaf(rl(t, k + 2), w2[k + 2], a2);
            a3 = fmaf(rl(t, k + 3), w2[k + 3], a3);
        }
        float h = bb2 + ((a0 + a1) + (a2 + a3));
        float p = h * wm;
#pragma unroll
        for (int o = 32; o >= 1; o >>= 1) p += __shfl_xor(p, o);
        if (lane == 0) score[node] += p;
        uin = unext;
    }
}

// ---------- edge softmax + new_score ----------
__global__ __launch_bounds__(256) void edge_softmax_kernel(const float* __restrict__ score,
                                                           const int* __restrict__ rowptr,
                                                           const int* __restrict__ csr_src,
                                                           const float* __restrict__ bm,
                                                           float* __restrict__ nsf, int N) {
    int wid = (blockIdx.x * blockDim.x + threadIdx.x) >> 6;
    int lane = threadIdx.x & 63;
    if (wid >= N) return;
    float b = bm[0];
    float sd = score[wid] + b;
    int start = rowptr[wid];
    int end = rowptr[wid + 1];
    bool has0 = (start + lane < end);
    float ss0 = 0.f;
    float m = -INFINITY;
    if (has0) {
        ss0 = score[csr_src[start + lane]] + b;
        m = ss0 * sd;
    }
    for (int j = start + 64 + lane; j < end; j += 64) {
        float ss = score[csr_src[j]] + b;
        m = fmaxf(m, ss * sd);
    }
#pragma unroll
    for (int o = 32; o >= 1; o >>= 1) m = fmaxf(m, __shfl_xor(m, o));
    float se = 0.f, swe = 0.f;
    if (m > -INFINITY) {
        if (has0) {
            float e0 = expf(ss0 * sd - m);
            se += e0;
            swe += ss0 * e0;
        }
        for (int j = start + 64 + lane; j < end; j += 64) {
            float ss = score[csr_src[j]] + b;
            float e = expf(ss * sd - m);
            se += e;
            swe += ss * e;
        }
#pragma unroll
        for (int o = 32; o >= 1; o >>= 1) {
            se += __shfl_xor(se, o);
            swe += __shfl_xor(swe, o);
        }
    }
    float ns = (se > 0.f) ? (swe / se) : 0.f;
    if (lane == 0) nsf[wid] = sd + ns;
}

// ---------- fused graph-segment softmax: one block per graph ----------
__global__ __launch_bounds__(256) void graph_softmax_kernel(const float* __restrict__ nsf,
                                                            const int* __restrict__ batch,
                                                            float* __restrict__ out, int N) {
    int g = blockIdx.x;
    int tid = threadIdx.x;
    int lo = 0, hi = N;
    while (lo < hi) { int mid = (lo + hi) >> 1; if (batch[mid] < g) lo = mid + 1; else hi = mid; }
    int s0 = lo;
    hi = N;
    while (lo < hi) { int mid = (lo + hi) >> 1; if (batch[mid] < g + 1) lo = mid + 1; else hi = mid; }
    int s1 = lo;

    __shared__ float red[4];
    __shared__ float bval;
    float m = -INFINITY;
    for (int i = s0 + tid; i < s1; i += 256) m = fmaxf(m, nsf[i]);
#pragma unroll
    for (int o = 32; o >= 1; o >>= 1) m = fmaxf(m, __shfl_xor(m, o));
    if ((tid & 63) == 0) red[tid >> 6] = m;
    __syncthreads();
    if (tid == 0) bval = fmaxf(fmaxf(red[0], red[1]), fmaxf(red[2], red[3]));
    __syncthreads();
    float bmx = bval;
    float s = 0.f;
    for (int i = s0 + tid; i < s1; i += 256) {
        float e = expf(nsf[i] - bmx);
        out[i] = e;
        s += e;
    }
#pragma unroll
    for (int o = 32; o >= 1; o >>= 1) s += __shfl_xor(s, o);
    __syncthreads();
    if ((tid & 63) == 0) red[tid >> 6] = s;
    __syncthreads();
    if (tid == 0) bval = red[0] + red[1] + red[2] + red[3];
    __syncthreads();
    float inv = 1.f / bval;
    for (int i = s0 + tid; i < s1; i += 256) out[i] *= inv;
}

extern "C" void kernel_launch(void* const* d_in, const int* in_sizes, int n_in,
                              void* d_out, int out_size, void* d_ws, size_t ws_size,
                              hipStream_t stream) {
    const int N = N_NODES, E = N_EDGES;

    const float* x = (const float*)d_in[0];
    const int* ei = (const int*)d_in[1];
    const int* batch = (const int*)d_in[2];
    const float* W1a[3] = {(const float*)d_in[3], (const float*)d_in[7], (const float*)d_in[11]};
    const float* b1a[3] = {(const float*)d_in[4], (const float*)d_in[8], (const float*)d_in[12]};
    const float* W2a[3] = {(const float*)d_in[5], (const float*)d_in[9], (const float*)d_in[13]};
    const float* b2a[3] = {(const float*)d_in[6], (const float*)d_in[10], (const float*)d_in[14]};
    const float* Wm = (const float*)d_in[15];
    const float* bm = (const float*)d_in[16];
    float* out = (float*)d_out;

    const int* srcp = ei;
    const int* dstp = ei + E;

    // workspace layout (~59 MB; csrc_chunk aliases ubuf — ubuf first written after gatherfill)
    float* ubuf = (float*)d_ws;                 // N*64 f32 (aliases csrc_chunk)
    int* csrc_chunk = (int*)ubuf;               // E ints (6.4MB of ubuf's 12.8MB)
    __half* yA = (__half*)(ubuf + (size_t)N * 64);  // N*64 f16
    __half* yB = yA + (size_t)N * 64;               // N*64 f16
    float* score = (float*)(yB + (size_t)N * 64);   // N
    float* nsf = score + N;                     // N
    int* deg = (int*)(nsf + N);                 // N
    int* rowptr = deg + N;                      // N+1
    int* part = rowptr + N + 1;                 // 64
    int* csr_src = part + 64;                   // E
    unsigned short* locs = (unsigned short*)(csr_src + E);        // CHUNKS*(N+1) u16
    unsigned short* base = locs + (size_t)CHUNKS * NP1;           // CHUNKS*N u16

    hist_gemm0_kernel<<<CHUNKS + GEMM_BLOCKS, 1024, 0, stream>>>(srcp, dstp, csrc_chunk, locs,
                                                                 x, W1a[0], yA, N);

    const int nbScan = (N + 1023) / 1024;  // 49
    base_scan1_kernel<<<nbScan, 1024, 0, stream>>>(locs, base, deg, part, N);
    scan2_kernel<<<1, 64, 0, stream>>>(part, nbScan);
    scan3_kernel<<<nbScan, 1024, 0, stream>>>(deg, part, rowptr, N);

    const int gfBlocks = 8 * ((N / 8 + 3) / 4);
    gatherfill_kernel<<<gfBlocks, 256, 0, stream>>>(csrc_chunk, locs, base, rowptr, csr_src);

    const int gw = 4096;
    int aggBlocks = (N + 3) / 4;  // one wave per node

    agg_kernel<<<aggBlocks, 256, 0, stream>>>(yA, rowptr, csr_src, ubuf, N);
    mlpAB_kernel<0><<<1024, 256, 0, stream>>>(ubuf, b1a[0], W2a[0], b2a[0], W1a[1], Wm, yB, score, N, gw);

    agg_kernel<<<aggBlocks, 256, 0, stream>>>(yB, rowptr, csr_src, ubuf, N);
    mlpAB_kernel<1><<<1024, 256, 0, stream>>>(ubuf, b1a[1], W2a[1], b2a[1], W1a[2], Wm, yA, score, N, gw);

    agg_kernel<<<aggBlocks, 256, 0, stream>>>(yA, rowptr, csr_src, ubuf, N);
    mlpA2_kernel<<<1024, 256, 0, stream>>>(ubuf, b1a[2], W2a[2], b2a[2], Wm, score, N, gw);

    edge_softmax_kernel<<<(N + 3) / 4, 256, 0, stream>>>(score, rowptr, csr_src, bm, nsf, N);

    graph_softmax_kernel<<<N_GRAPH, 256, 0, stream>>>(nsf, batch, out, N);
}

// Round 13
// 356.917 us; speedup vs baseline: 1.0437x; 1.0437x over previous
//
#include <hip/hip_runtime.h>
#include <hip/hip_fp16.h>
#include <math.h>

#define N_NODES 50000
#define N_EDGES 1600000
#define N_GRAPH 500
#define CHUNKS 128
#define EPC (N_EDGES / CHUNKS)  // 12500 edges per chunk
#define NP1 (N_NODES + 1)
#define NIT ((EPC + 1023) / 1024)  // 13 edge-iterations per histsort thread
#define GEMM_BLOCKS 1024

// ---------- helpers ----------
__device__ __forceinline__ float rl(float v, int k) {
    return __int_as_float(__builtin_amdgcn_readlane(__float_as_int(v), k));
}
// accumulate 8 fp16 (uint4) into two float4
__device__ __forceinline__ void hacc16(float4& A, float4& B, uint4 w) {
    float2 f0 = __half22float2(*reinterpret_cast<__half2*>(&w.x));
    float2 f1 = __half22float2(*reinterpret_cast<__half2*>(&w.y));
    float2 f2 = __half22float2(*reinterpret_cast<__half2*>(&w.z));
    float2 f3 = __half22float2(*reinterpret_cast<__half2*>(&w.w));
    A.x += f0.x; A.y += f0.y; A.z += f1.x; A.w += f1.y;
    B.x += f2.x; B.y += f2.y; B.z += f3.x; B.w += f3.y;
}

// ---------- histsort: per-chunk LDS histogram -> in-LDS scan -> chunk-local
//            dst-sorted scatter. Local ranks in registers. No global atomics.
__global__ __launch_bounds__(1024) void histsort_kernel(const int* __restrict__ src,
                                                        const int* __restrict__ dst,
                                                        int* __restrict__ csrc_chunk,
                                                        unsigned short* __restrict__ locs) {
    __shared__ unsigned packed[N_NODES / 2];  // 100 KB
    __shared__ unsigned aux[1024];
    const int c = blockIdx.x;
    const int s0 = c * EPC;
    const int tid = threadIdx.x;

    for (int i = tid; i < N_NODES / 2; i += 1024) packed[i] = 0;
    __syncthreads();

    unsigned short lrv[NIT];
#pragma unroll
    for (int it = 0; it < NIT; it++) {
        int e = s0 + it * 1024 + tid;
        if (e < s0 + EPC) {
            int d = dst[e];
            int sh = (d & 1) * 16;
            unsigned old = atomicAdd(&packed[d >> 1], 1u << sh);
            lrv[it] = (unsigned short)((old >> sh) & 0xffffu);
        }
    }
    __syncthreads();

    const int W = 25;
    int w0 = tid * W;
    int w1 = min(w0 + W, N_NODES / 2);
    unsigned run = 0;
    for (int i = w0; i < w1; i++) {
        unsigned v = packed[i];
        unsigned lo = v & 0xffffu, hi = v >> 16;
        packed[i] = run | ((run + lo) << 16);
        run += lo + hi;
    }
    aux[tid] = run;
    __syncthreads();
    for (int off = 1; off < 1024; off <<= 1) {
        unsigned t = (tid >= off) ? aux[tid - off] : 0;
        __syncthreads();
        aux[tid] += t;
        __syncthreads();
    }
    unsigned b0 = (tid == 0) ? 0 : aux[tid - 1];
    if (b0) {
        unsigned addv = b0 | (b0 << 16);
        for (int i = w0; i < w1; i++) packed[i] += addv;
    }
    __syncthreads();

    int* outc = csrc_chunk + (size_t)c * EPC;
#pragma unroll
    for (int it = 0; it < NIT; it++) {
        int e = s0 + it * 1024 + tid;
        if (e < s0 + EPC) {
            int d = dst[e];
            unsigned pw = packed[d >> 1];
            unsigned loc = (d & 1) ? (pw >> 16) : (pw & 0xffffu);
            outc[loc + lrv[it]] = src[e];
        }
    }
    unsigned short* lc = locs + (size_t)c * NP1;
    for (int d = tid; d <= N_NODES; d += 1024) {
        unsigned short loc;
        if (d == N_NODES) {
            loc = (unsigned short)EPC;
        } else {
            unsigned pw = packed[d >> 1];
            loc = (unsigned short)((d & 1) ? (pw >> 16) : (pw & 0xffffu));
        }
        lc[d] = loc;
    }
}

// ---------- base + scan1 fused ----------
__global__ __launch_bounds__(1024) void base_scan1_kernel(const unsigned short* __restrict__ locs,
                                                          unsigned short* __restrict__ base,
                                                          int* __restrict__ deg,
                                                          int* __restrict__ part, int N) {
    int d = blockIdx.x * 1024 + threadIdx.x;
    int run = 0;
    if (d < N) {
#pragma unroll 8
        for (int c = 0; c < CHUNKS; c++) {
            int l0 = locs[(size_t)c * NP1 + d];
            int l1 = locs[(size_t)c * NP1 + d + 1];
            base[(size_t)c * N + d] = (unsigned short)run;
            run += l1 - l0;
        }
        deg[d] = run;
    }
    int v = run;
#pragma unroll
    for (int o = 32; o >= 1; o >>= 1) v += __shfl_xor(v, o);
    __shared__ int red[16];
    if ((threadIdx.x & 63) == 0) red[threadIdx.x >> 6] = v;
    __syncthreads();
    if (threadIdx.x == 0) {
        int s = 0;
#pragma unroll
        for (int k = 0; k < 16; k++) s += red[k];
        part[blockIdx.x] = s;
    }
}

// ---------- scan3 with self-computed block offset (scan2 eliminated) ----------
__global__ __launch_bounds__(1024) void scan3_kernel(const int* __restrict__ deg,
                                                     const int* __restrict__ part,
                                                     int* __restrict__ rowptr, int N, int nb) {
    __shared__ int blockOff;
    __shared__ int wsum[16];
    int lane = threadIdx.x & 63;
    int w = threadIdx.x >> 6;
    if (threadIdx.x < 64) {
        int pv = (lane < nb && lane < (int)blockIdx.x) ? part[lane] : 0;
#pragma unroll
        for (int o = 32; o >= 1; o >>= 1) pv += __shfl_xor(pv, o);
        if (lane == 0) blockOff = pv;
    }
    int i = blockIdx.x * 1024 + threadIdx.x;
    int v = (i < N) ? deg[i] : 0;
    int inc = v;
#pragma unroll
    for (int o = 1; o < 64; o <<= 1) {
        int t = __shfl_up(inc, o);
        if (lane >= o) inc += t;
    }
    if (lane == 63) wsum[w] = inc;
    __syncthreads();
    if (threadIdx.x < 16) {
        int x = wsum[threadIdx.x];
        int xo = x;
#pragma unroll
        for (int o = 1; o < 16; o <<= 1) {
            int t = __shfl_up(x, o);
            if ((int)threadIdx.x >= o) x += t;
        }
        wsum[threadIdx.x] = x - xo;
    }
    __syncthreads();
    int b = blockOff + wsum[w];
    if (i < N) {
        rowptr[i] = b + inc - v;
        if (i == N - 1) rowptr[N] = b + inc;
    }
}

// ---------- merged gatherfill + gemm0 (no LDS, both 256-thread paths) ----------
// blocks [0, gfBlocks): gatherfill; [gfBlocks, gfBlocks+GEMM_BLOCKS): gemm0.
__global__ __launch_bounds__(256) void gf_gemm0_kernel(const int* __restrict__ csrc_chunk,
                                                       const unsigned short* __restrict__ locs,
                                                       const unsigned short* __restrict__ base,
                                                       const int* __restrict__ rowptr,
                                                       int* __restrict__ csr_src,
                                                       const float* __restrict__ x,
                                                       const float* __restrict__ W1,
                                                       __half* __restrict__ y0,
                                                       int gfBlocks, int N) {
    if ((int)blockIdx.x < gfBlocks) {
        // ---- gatherfill: one wave per node, lane covers 2 chunks ----
        const int perXcd = N_NODES / 8;  // 6250
        int xcd = blockIdx.x & 7;
        int idx = (blockIdx.x >> 3) * 4 + (threadIdx.x >> 6);
        if (idx >= perXcd) return;
        int wid = xcd * perXcd + idx;
        int lane = threadIdx.x & 63;
        int rp = rowptr[wid];
#pragma unroll
        for (int cc = 0; cc < 2; cc++) {
            int c = lane + cc * 64;
            const unsigned short* lc = locs + (size_t)c * NP1;
            int l0 = lc[wid];
            int l1 = lc[wid + 1];
            int cnt = l1 - l0;
            int ob = rp + (int)base[(size_t)c * N_NODES + wid];
            const int* in = csrc_chunk + (size_t)c * EPC + l0;
            for (int i = 0; i < cnt; i++) csr_src[ob + i] = in[i];
        }
    } else {
        // ---- gemm0: y0 = x @ W1_0, 2 K-half passes, w[64] registers ----
        int lane = threadIdx.x & 63;
        int wid = (((int)blockIdx.x - gfBlocks) * 256 + threadIdx.x) >> 6;
        const int totalWaves = GEMM_BLOCKS * 4;
        float w[64];
#pragma unroll
        for (int k = 0; k < 64; k++) w[k] = W1[k * 64 + lane];
        for (int node = wid; node < N; node += totalWaves) {
            float xa = x[(size_t)node * 128 + lane];
            float a0 = 0.f, a1 = 0.f, a2 = 0.f, a3 = 0.f;
#pragma unroll
            for (int k = 0; k < 64; k += 4) {
                a0 = fmaf(rl(xa, k + 0), w[k + 0], a0);
                a1 = fmaf(rl(xa, k + 1), w[k + 1], a1);
                a2 = fmaf(rl(xa, k + 2), w[k + 2], a2);
                a3 = fmaf(rl(xa, k + 3), w[k + 3], a3);
            }
            // store fp32 partial into y0 as fp16 later; keep partial in fp16 temp:
            y0[(size_t)node * 64 + lane] = __float2half((a0 + a1) + (a2 + a3));
        }
#pragma unroll
        for (int k = 0; k < 64; k++) w[k] = W1[(64 + k) * 64 + lane];
        for (int node = wid; node < N; node += totalWaves) {
            float xb = x[(size_t)node * 128 + 64 + lane];
            float a0 = 0.f, a1 = 0.f, a2 = 0.f, a3 = 0.f;
#pragma unroll
            for (int k = 0; k < 64; k += 4) {
                a0 = fmaf(rl(xb, k + 0), w[k + 0], a0);
                a1 = fmaf(rl(xb, k + 1), w[k + 1], a1);
                a2 = fmaf(rl(xb, k + 2), w[k + 2], a2);
                a3 = fmaf(rl(xb, k + 3), w[k + 3], a3);
            }
            float prev = __half2float(y0[(size_t)node * 64 + lane]);
            y0[(size_t)node * 64 + lane] = __float2half(prev + ((a0 + a1) + (a2 + a3)));
        }
    }
}

// ---------- aggregation on fp16 y: uint4 loads, 8 edge slots, fp32 accum ----------
__global__ __launch_bounds__(256) void agg_kernel(const __half* __restrict__ yh,
                                                  const int* __restrict__ rowptr,
                                                  const int* __restrict__ csr_src,
                                                  float* __restrict__ u, int N) {
    int wid = (blockIdx.x * 256 + threadIdx.x) >> 6;
    int lane = threadIdx.x & 63;
    if (wid >= N) return;
    int q = lane >> 3;  // edge slot 0..7
    int r = lane & 7;   // feature oct 0..7 (8 halves = 16B each)
    int start = rowptr[wid];
    int end = rowptr[wid + 1];
    float4 A = make_float4(0.f, 0.f, 0.f, 0.f);
    float4 B = make_float4(0.f, 0.f, 0.f, 0.f);
    int j = start;
    for (; j + 64 <= end; j += 64) {
        int s0 = csr_src[j + q];
        int s1 = csr_src[j + 8 + q];
        int s2 = csr_src[j + 16 + q];
        int s3 = csr_src[j + 24 + q];
        int s4 = csr_src[j + 32 + q];
        int s5 = csr_src[j + 40 + q];
        int s6 = csr_src[j + 48 + q];
        int s7 = csr_src[j + 56 + q];
        uint4 w0 = *(const uint4*)(yh + (size_t)s0 * 64 + r * 8);
        uint4 w1 = *(const uint4*)(yh + (size_t)s1 * 64 + r * 8);
        uint4 w2 = *(const uint4*)(yh + (size_t)s2 * 64 + r * 8);
        uint4 w3 = *(const uint4*)(yh + (size_t)s3 * 64 + r * 8);
        uint4 w4 = *(const uint4*)(yh + (size_t)s4 * 64 + r * 8);
        uint4 w5 = *(const uint4*)(yh + (size_t)s5 * 64 + r * 8);
        uint4 w6 = *(const uint4*)(yh + (size_t)s6 * 64 + r * 8);
        uint4 w7 = *(const uint4*)(yh + (size_t)s7 * 64 + r * 8);
        hacc16(A, B, w0); hacc16(A, B, w1); hacc16(A, B, w2); hacc16(A, B, w3);
        hacc16(A, B, w4); hacc16(A, B, w5); hacc16(A, B, w6); hacc16(A, B, w7);
    }
#pragma unroll
    for (int m = 0; m < 8; m++) {
        int e = j + 8 * m + q;
        if (e < end) {
            int s = csr_src[e];
            uint4 w = *(const uint4*)(yh + (size_t)s * 64 + r * 8);
            hacc16(A, B, w);
        }
    }
#pragma unroll
    for (int o = 8; o <= 32; o <<= 1) {
        A.x += __shfl_xor(A.x, o); A.y += __shfl_xor(A.y, o);
        A.z += __shfl_xor(A.z, o); A.w += __shfl_xor(A.w, o);
        B.x += __shfl_xor(B.x, o); B.y += __shfl_xor(B.y, o);
        B.z += __shfl_xor(B.z, o); B.w += __shfl_xor(B.w, o);
    }
    if (lane < 8) {
        uint4 w = *(const uint4*)(yh + (size_t)wid * 64 + r * 8);
        hacc16(A, B, w);
        *(float4*)(u + (size_t)wid * 64 + r * 8) = A;
        *(float4*)(u + (size_t)wid * 64 + r * 8 + 4) = B;
    }
}

// ---------- fused mlpAB (layers 0,1): fp32 u in, fp16 ynext out ----------
template <int LAYER>
__global__ __launch_bounds__(256) void mlpAB_kernel(const float* __restrict__ u,
                                                    const float* __restrict__ b1,
                                                    const float* __restrict__ W2,
                                                    const float* __restrict__ b2,
                                                    const float* __restrict__ W1n,
                                                    const float* __restrict__ Wm,
                                                    __half* __restrict__ ynext,
                                                    float* __restrict__ score,
                                                    int N, int totalWaves) {
    int lane = threadIdx.x & 63;
    int wid = (blockIdx.x * 256 + threadIdx.x) >> 6;
    float w2[64], w1[64];
#pragma unroll
    for (int k = 0; k < 64; k++) w2[k] = W2[k * 64 + lane];
#pragma unroll
    for (int k = 0; k < 64; k++) w1[k] = W1n[k * 64 + lane];
    float bb1 = b1[lane], bb2 = b2[lane], wm = Wm[LAYER * 64 + lane];

    int node = wid;
    float uin = (node < N) ? u[(size_t)node * 64 + lane] : 0.f;
    for (; node < N; node += totalWaves) {
        int nn = node + totalWaves;
        float unext = (nn < N) ? u[(size_t)nn * 64 + lane] : 0.f;
        float t = fmaxf(uin + bb1, 0.f);
        float a0 = 0.f, a1 = 0.f, a2 = 0.f, a3 = 0.f;
#pragma unroll
        for (int k = 0; k < 64; k += 4) {
            a0 = fmaf(rl(t, k + 0), w2[k + 0], a0);
            a1 = fmaf(rl(t, k + 1), w2[k + 1], a1);
            a2 = fmaf(rl(t, k + 2), w2[k + 2], a2);
            a3 = fmaf(rl(t, k + 3), w2[k + 3], a3);
        }
        float h = fmaxf(bb2 + ((a0 + a1) + (a2 + a3)), 0.f);
        float p = h * wm;
#pragma unroll
        for (int o = 32; o >= 1; o >>= 1) p += __shfl_xor(p, o);
        if (lane == 0) {
            if (LAYER == 0) score[node] = p;
            else score[node] += p;
        }
        float y0 = 0.f, y1 = 0.f, y2 = 0.f, y3 = 0.f;
#pragma unroll
        for (int k = 0; k < 64; k += 4) {
            y0 = fmaf(rl(h, k + 0), w1[k + 0], y0);
            y1 = fmaf(rl(h, k + 1), w1[k + 1], y1);
            y2 = fmaf(rl(h, k + 2), w1[k + 2], y2);
            y3 = fmaf(rl(h, k + 3), w1[k + 3], y3);
        }
        ynext[(size_t)node * 64 + lane] = __float2half((y0 + y1) + (y2 + y3));
        uin = unext;
    }
}

// ---------- mlpA2 (layer 2) ----------
__global__ __launch_bounds__(256) void mlpA2_kernel(const float* __restrict__ u,
                                                    const float* __restrict__ b1,
                                                    const float* __restrict__ W2,
                                                    const float* __restrict__ b2,
                                                    const float* __restrict__ Wm,
                                                    float* __restrict__ score,
                                                    int N, int totalWaves) {
    int lane = threadIdx.x & 63;
    int wid = (blockIdx.x * 256 + threadIdx.x) >> 6;
    float w2[64];
#pragma unroll
    for (int k = 0; k < 64; k++) w2[k] = W2[k * 64 + lane];
    float bb1 = b1[lane], bb2 = b2[lane], wm = Wm[2 * 64 + lane];

    int node = wid;
    float uin = (node < N) ? u[(size_t)node * 64 + lane] : 0.f;
    for (; node < N; node += totalWaves) {
        int nn = node + totalWaves;
        float unext = (nn < N) ? u[(size_t)nn * 64 + lane] : 0.f;
        float t = fmaxf(uin + bb1, 0.f);
        float a0 = 0.f, a1 = 0.f, a2 = 0.f, a3 = 0.f;
#pragma unroll
        for (int k = 0; k < 64; k += 4) {
            a0 = fmaf(rl(t, k + 0), w2[k + 0], a0);
            a1 = fmaf(rl(t, k + 1), w2[k + 1], a1);
            a2 = fmaf(rl(t, k + 2), w2[k + 2], a2);
            a3 = fmaf(rl(t, k + 3), w2[k + 3], a3);
        }
        float h = bb2 + ((a0 + a1) + (a2 + a3));
        float p = h * wm;
#pragma unroll
        for (int o = 32; o >= 1; o >>= 1) p += __shfl_xor(p, o);
        if (lane == 0) score[node] += p;
        uin = unext;
    }
}

// ---------- edge softmax + new_score ----------
__global__ __launch_bounds__(256) void edge_softmax_kernel(const float* __restrict__ score,
                                                           const int* __restrict__ rowptr,
                                                           const int* __restrict__ csr_src,
                                                           const float* __restrict__ bm,
                                                           float* __restrict__ nsf, int N) {
    int wid = (blockIdx.x * blockDim.x + threadIdx.x) >> 6;
    int lane = threadIdx.x & 63;
    if (wid >= N) return;
    float b = bm[0];
    float sd = score[wid] + b;
    int start = rowptr[wid];
    int end = rowptr[wid + 1];
    bool has0 = (start + lane < end);
    float ss0 = 0.f;
    float m = -INFINITY;
    if (has0) {
        ss0 = score[csr_src[start + lane]] + b;
        m = ss0 * sd;
    }
    for (int j = start + 64 + lane; j < end; j += 64) {
        float ss = score[csr_src[j]] + b;
        m = fmaxf(m, ss * sd);
    }
#pragma unroll
    for (int o = 32; o >= 1; o >>= 1) m = fmaxf(m, __shfl_xor(m, o));
    float se = 0.f, swe = 0.f;
    if (m > -INFINITY) {
        if (has0) {
            float e0 = expf(ss0 * sd - m);
            se += e0;
            swe += ss0 * e0;
        }
        for (int j = start + 64 + lane; j < end; j += 64) {
            float ss = score[csr_src[j]] + b;
            float e = expf(ss * sd - m);
            se += e;
            swe += ss * e;
        }
#pragma unroll
        for (int o = 32; o >= 1; o >>= 1) {
            se += __shfl_xor(se, o);
            swe += __shfl_xor(swe, o);
        }
    }
    float ns = (se > 0.f) ? (swe / se) : 0.f;
    if (lane == 0) nsf[wid] = sd + ns;
}

// ---------- fused graph-segment softmax: one block per graph ----------
__global__ __launch_bounds__(256) void graph_softmax_kernel(const float* __restrict__ nsf,
                                                            const int* __restrict__ batch,
                                                            float* __restrict__ out, int N) {
    int g = blockIdx.x;
    int tid = threadIdx.x;
    int lo = 0, hi = N;
    while (lo < hi) { int mid = (lo + hi) >> 1; if (batch[mid] < g) lo = mid + 1; else hi = mid; }
    int s0 = lo;
    hi = N;
    while (lo < hi) { int mid = (lo + hi) >> 1; if (batch[mid] < g + 1) lo = mid + 1; else hi = mid; }
    int s1 = lo;

    __shared__ float red[4];
    __shared__ float bval;
    float m = -INFINITY;
    for (int i = s0 + tid; i < s1; i += 256) m = fmaxf(m, nsf[i]);
#pragma unroll
    for (int o = 32; o >= 1; o >>= 1) m = fmaxf(m, __shfl_xor(m, o));
    if ((tid & 63) == 0) red[tid >> 6] = m;
    __syncthreads();
    if (tid == 0) bval = fmaxf(fmaxf(red[0], red[1]), fmaxf(red[2], red[3]));
    __syncthreads();
    float bmx = bval;
    float s = 0.f;
    for (int i = s0 + tid; i < s1; i += 256) {
        float e = expf(nsf[i] - bmx);
        out[i] = e;
        s += e;
    }
#pragma unroll
    for (int o = 32; o >= 1; o >>= 1) s += __shfl_xor(s, o);
    __syncthreads();
    if ((tid & 63) == 0) red[tid >> 6] = s;
    __syncthreads();
    if (tid == 0) bval = red[0] + red[1] + red[2] + red[3];
    __syncthreads();
    float inv = 1.f / bval;
    for (int i = s0 + tid; i < s1; i += 256) out[i] *= inv;
}

extern "C" void kernel_launch(void* const* d_in, const int* in_sizes, int n_in,
                              void* d_out, int out_size, void* d_ws, size_t ws_size,
                              hipStream_t stream) {
    const int N = N_NODES, E = N_EDGES;

    const float* x = (const float*)d_in[0];
    const int* ei = (const int*)d_in[1];
    const int* batch = (const int*)d_in[2];
    const float* W1a[3] = {(const float*)d_in[3], (const float*)d_in[7], (const float*)d_in[11]};
    const float* b1a[3] = {(const float*)d_in[4], (const float*)d_in[8], (const float*)d_in[12]};
    const float* W2a[3] = {(const float*)d_in[5], (const float*)d_in[9], (const float*)d_in[13]};
    const float* b2a[3] = {(const float*)d_in[6], (const float*)d_in[10], (const float*)d_in[14]};
    const float* Wm = (const float*)d_in[15];
    const float* bm = (const float*)d_in[16];
    float* out = (float*)d_out;

    const int* srcp = ei;
    const int* dstp = ei + E;

    // workspace layout (~59 MB; csrc_chunk aliases ubuf — ubuf first written after gatherfill)
    float* ubuf = (float*)d_ws;                 // N*64 f32 (aliases csrc_chunk)
    int* csrc_chunk = (int*)ubuf;               // E ints (6.4MB of ubuf's 12.8MB)
    __half* yA = (__half*)(ubuf + (size_t)N * 64);  // N*64 f16
    __half* yB = yA + (size_t)N * 64;               // N*64 f16
    float* score = (float*)(yB + (size_t)N * 64);   // N
    float* nsf = score + N;                     // N
    int* deg = (int*)(nsf + N);                 // N
    int* rowptr = deg + N;                      // N+1
    int* part = rowptr + N + 1;                 // 64
    int* csr_src = part + 64;                   // E
    unsigned short* locs = (unsigned short*)(csr_src + E);        // CHUNKS*(N+1) u16
    unsigned short* base = locs + (size_t)CHUNKS * NP1;           // CHUNKS*N u16

    histsort_kernel<<<CHUNKS, 1024, 0, stream>>>(srcp, dstp, csrc_chunk, locs);

    const int nbScan = (N + 1023) / 1024;  // 49
    base_scan1_kernel<<<nbScan, 1024, 0, stream>>>(locs, base, deg, part, N);
    scan3_kernel<<<nbScan, 1024, 0, stream>>>(deg, part, rowptr, N, nbScan);

    const int gfBlocks = 8 * ((N / 8 + 3) / 4);  // 12504
    gf_gemm0_kernel<<<gfBlocks + GEMM_BLOCKS, 256, 0, stream>>>(csrc_chunk, locs, base, rowptr,
                                                                csr_src, x, W1a[0], yA, gfBlocks, N);

    const int gw = 4096;
    int aggBlocks = (N + 3) / 4;  // one wave per node

    agg_kernel<<<aggBlocks, 256, 0, stream>>>(yA, rowptr, csr_src, ubuf, N);
    mlpAB_kernel<0><<<1024, 256, 0, stream>>>(ubuf, b1a[0], W2a[0], b2a[0], W1a[1], Wm, yB, score, N, gw);

    agg_kernel<<<aggBlocks, 256, 0, stream>>>(yB, rowptr, csr_src, ubuf, N);
    mlpAB_kernel<1><<<1024, 256, 0, stream>>>(ubuf, b1a[1], W2a[1], b2a[1], W1a[2], Wm, yA, score, N, gw);

    agg_kernel<<<aggBlocks, 256, 0, stream>>>(yA, rowptr, csr_src, ubuf, N);
    mlpA2_kernel<<<1024, 256, 0, stream>>>(ubuf, b1a[2], W2a[2], b2a[2], Wm, score, N, gw);

    edge_softmax_kernel<<<(N + 3) / 4, 256, 0, stream>>>(score, rowptr, csr_src, bm, nsf, N);

    graph_softmax_kernel<<<N_GRAPH, 256, 0, stream>>>(nsf, batch, out, N);
}

// Round 14
// 348.992 us; speedup vs baseline: 1.0674x; 1.0227x over previous
//
#include <hip/hip_runtime.h>
#include <hip/hip_fp16.h>
#include <math.h>

#define N_NODES 50000
#define N_EDGES 1600000
#define N_GRAPH 500
#define CHUNKS 128
#define EPC (N_EDGES / CHUNKS)  // 12500 edges per chunk
#define NP1 (N_NODES + 1)
#define NIT ((EPC + 1023) / 1024)  // 13 edge-iterations per histsort thread

// ---------- helpers ----------
__device__ __forceinline__ float rl(float v, int k) {
    return __int_as_float(__builtin_amdgcn_readlane(__float_as_int(v), k));
}
// accumulate 8 fp16 (uint4) into two float4
__device__ __forceinline__ void hacc16(float4& A, float4& B, uint4 w) {
    float2 f0 = __half22float2(*reinterpret_cast<__half2*>(&w.x));
    float2 f1 = __half22float2(*reinterpret_cast<__half2*>(&w.y));
    float2 f2 = __half22float2(*reinterpret_cast<__half2*>(&w.z));
    float2 f3 = __half22float2(*reinterpret_cast<__half2*>(&w.w));
    A.x += f0.x; A.y += f0.y; A.z += f1.x; A.w += f1.y;
    B.x += f2.x; B.y += f2.y; B.z += f3.x; B.w += f3.y;
}

// ---------- histsort: per-chunk LDS histogram -> in-LDS scan -> chunk-local
//            dst-sorted scatter. Local ranks in registers. No global atomics.
__global__ __launch_bounds__(1024) void histsort_kernel(const int* __restrict__ src,
                                                        const int* __restrict__ dst,
                                                        int* __restrict__ csrc_chunk,
                                                        unsigned short* __restrict__ locs) {
    __shared__ unsigned packed[N_NODES / 2];  // 100 KB
    __shared__ unsigned aux[1024];
    const int c = blockIdx.x;
    const int s0 = c * EPC;
    const int tid = threadIdx.x;

    for (int i = tid; i < N_NODES / 2; i += 1024) packed[i] = 0;
    __syncthreads();

    unsigned short lrv[NIT];
#pragma unroll
    for (int it = 0; it < NIT; it++) {
        int e = s0 + it * 1024 + tid;
        if (e < s0 + EPC) {
            int d = dst[e];
            int sh = (d & 1) * 16;
            unsigned old = atomicAdd(&packed[d >> 1], 1u << sh);
            lrv[it] = (unsigned short)((old >> sh) & 0xffffu);
        }
    }
    __syncthreads();

    const int W = 25;
    int w0 = tid * W;
    int w1 = min(w0 + W, N_NODES / 2);
    unsigned run = 0;
    for (int i = w0; i < w1; i++) {
        unsigned v = packed[i];
        unsigned lo = v & 0xffffu, hi = v >> 16;
        packed[i] = run | ((run + lo) << 16);
        run += lo + hi;
    }
    aux[tid] = run;
    __syncthreads();
    for (int off = 1; off < 1024; off <<= 1) {
        unsigned t = (tid >= off) ? aux[tid - off] : 0;
        __syncthreads();
        aux[tid] += t;
        __syncthreads();
    }
    unsigned b0 = (tid == 0) ? 0 : aux[tid - 1];
    if (b0) {
        unsigned addv = b0 | (b0 << 16);
        for (int i = w0; i < w1; i++) packed[i] += addv;
    }
    __syncthreads();

    int* outc = csrc_chunk + (size_t)c * EPC;
#pragma unroll
    for (int it = 0; it < NIT; it++) {
        int e = s0 + it * 1024 + tid;
        if (e < s0 + EPC) {
            int d = dst[e];
            unsigned pw = packed[d >> 1];
            unsigned loc = (d & 1) ? (pw >> 16) : (pw & 0xffffu);
            outc[loc + lrv[it]] = src[e];
        }
    }
    unsigned short* lc = locs + (size_t)c * NP1;
    for (int d = tid; d <= N_NODES; d += 1024) {
        unsigned short loc;
        if (d == N_NODES) {
            loc = (unsigned short)EPC;
        } else {
            unsigned pw = packed[d >> 1];
            loc = (unsigned short)((d & 1) ? (pw >> 16) : (pw & 0xffffu));
        }
        lc[d] = loc;
    }
}

// ---------- base + scan1 fused ----------
__global__ __launch_bounds__(1024) void base_scan1_kernel(const unsigned short* __restrict__ locs,
                                                          unsigned short* __restrict__ base,
                                                          int* __restrict__ deg,
                                                          int* __restrict__ part, int N) {
    int d = blockIdx.x * 1024 + threadIdx.x;
    int run = 0;
    if (d < N) {
#pragma unroll 8
        for (int c = 0; c < CHUNKS; c++) {
            int l0 = locs[(size_t)c * NP1 + d];
            int l1 = locs[(size_t)c * NP1 + d + 1];
            base[(size_t)c * N + d] = (unsigned short)run;
            run += l1 - l0;
        }
        deg[d] = run;
    }
    int v = run;
#pragma unroll
    for (int o = 32; o >= 1; o >>= 1) v += __shfl_xor(v, o);
    __shared__ int red[16];
    if ((threadIdx.x & 63) == 0) red[threadIdx.x >> 6] = v;
    __syncthreads();
    if (threadIdx.x == 0) {
        int s = 0;
#pragma unroll
        for (int k = 0; k < 16; k++) s += red[k];
        part[blockIdx.x] = s;
    }
}

// ---------- scan3 with self-computed block offset (no scan2 launch) ----------
__global__ __launch_bounds__(1024) void scan3_kernel(const int* __restrict__ deg,
                                                     const int* __restrict__ part,
                                                     int* __restrict__ rowptr, int N, int nb) {
    __shared__ int blockOff;
    __shared__ int wsum[16];
    int lane = threadIdx.x & 63;
    int w = threadIdx.x >> 6;
    if (threadIdx.x < 64) {
        int pv = (lane < nb && lane < (int)blockIdx.x) ? part[lane] : 0;
#pragma unroll
        for (int o = 32; o >= 1; o >>= 1) pv += __shfl_xor(pv, o);
        if (lane == 0) blockOff = pv;
    }
    int i = blockIdx.x * 1024 + threadIdx.x;
    int v = (i < N) ? deg[i] : 0;
    int inc = v;
#pragma unroll
    for (int o = 1; o < 64; o <<= 1) {
        int t = __shfl_up(inc, o);
        if (lane >= o) inc += t;
    }
    if (lane == 63) wsum[w] = inc;
    __syncthreads();
    if (threadIdx.x < 16) {
        int x = wsum[threadIdx.x];
        int xo = x;
#pragma unroll
        for (int o = 1; o < 16; o <<= 1) {
            int t = __shfl_up(x, o);
            if ((int)threadIdx.x >= o) x += t;
        }
        wsum[threadIdx.x] = x - xo;
    }
    __syncthreads();
    int b = blockOff + wsum[w];
    if (i < N) {
        rowptr[i] = b + inc - v;
        if (i == N - 1) rowptr[N] = b + inc;
    }
}

// ---------- gatherfill: one wave per node, lane covers 2 chunks ----------
__global__ __launch_bounds__(256) void gatherfill_kernel(const int* __restrict__ csrc_chunk,
                                                         const unsigned short* __restrict__ locs,
                                                         const unsigned short* __restrict__ base,
                                                         const int* __restrict__ rowptr,
                                                         int* __restrict__ csr_src) {
    const int perXcd = N_NODES / 8;  // 6250
    int xcd = blockIdx.x & 7;
    int idx = (blockIdx.x >> 3) * 4 + (threadIdx.x >> 6);
    if (idx >= perXcd) return;
    int wid = xcd * perXcd + idx;
    int lane = threadIdx.x & 63;
    int rp = rowptr[wid];
#pragma unroll
    for (int cc = 0; cc < 2; cc++) {
        int c = lane + cc * 64;
        const unsigned short* lc = locs + (size_t)c * NP1;
        int l0 = lc[wid];
        int l1 = lc[wid + 1];
        int cnt = l1 - l0;
        int ob = rp + (int)base[(size_t)c * N_NODES + wid];
        const int* in = csrc_chunk + (size_t)c * EPC + l0;
        for (int i = 0; i < cnt; i++) csr_src[ob + i] = in[i];
    }
}

// ---------- gemm0: y0 = x @ W1_0, both K-halves in registers, fp16 store ----------
__global__ __launch_bounds__(256) void gemm0_kernel(const float* __restrict__ x,
                                                    const float* __restrict__ W1,
                                                    __half* __restrict__ y0,
                                                    int N, int totalWaves) {
    int lane = threadIdx.x & 63;
    int wid = (blockIdx.x * 256 + threadIdx.x) >> 6;
    float wA[64], wB[64];
#pragma unroll
    for (int k = 0; k < 64; k++) wA[k] = W1[k * 64 + lane];
#pragma unroll
    for (int k = 0; k < 64; k++) wB[k] = W1[(64 + k) * 64 + lane];
    for (int node = wid; node < N; node += totalWaves) {
        float xa = x[(size_t)node * 128 + lane];
        float xb = x[(size_t)node * 128 + 64 + lane];
        float a0 = 0.f, a1 = 0.f, a2 = 0.f, a3 = 0.f;
#pragma unroll
        for (int k = 0; k < 64; k += 4) {
            a0 = fmaf(rl(xa, k + 0), wA[k + 0], a0);
            a1 = fmaf(rl(xa, k + 1), wA[k + 1], a1);
            a2 = fmaf(rl(xa, k + 2), wA[k + 2], a2);
            a3 = fmaf(rl(xa, k + 3), wA[k + 3], a3);
        }
#pragma unroll
        for (int k = 0; k < 64; k += 4) {
            a0 = fmaf(rl(xb, k + 0), wB[k + 0], a0);
            a1 = fmaf(rl(xb, k + 1), wB[k + 1], a1);
            a2 = fmaf(rl(xb, k + 2), wB[k + 2], a2);
            a3 = fmaf(rl(xb, k + 3), wB[k + 3], a3);
        }
        y0[(size_t)node * 64 + lane] = __float2half((a0 + a1) + (a2 + a3));
    }
}

// ---------- aggregation on fp16 y: uint4 loads, 8 edge slots, fp32 accum ----------
__global__ __launch_bounds__(256) void agg_kernel(const __half* __restrict__ yh,
                                                  const int* __restrict__ rowptr,
                                                  const int* __restrict__ csr_src,
                                                  float* __restrict__ u, int N) {
    int wid = (blockIdx.x * 256 + threadIdx.x) >> 6;
    int lane = threadIdx.x & 63;
    if (wid >= N) return;
    int q = lane >> 3;  // edge slot 0..7
    int r = lane & 7;   // feature oct 0..7 (8 halves = 16B each)
    int start = rowptr[wid];
    int end = rowptr[wid + 1];
    float4 A = make_float4(0.f, 0.f, 0.f, 0.f);
    float4 B = make_float4(0.f, 0.f, 0.f, 0.f);
    int j = start;
    for (; j + 64 <= end; j += 64) {
        int s0 = csr_src[j + q];
        int s1 = csr_src[j + 8 + q];
        int s2 = csr_src[j + 16 + q];
        int s3 = csr_src[j + 24 + q];
        int s4 = csr_src[j + 32 + q];
        int s5 = csr_src[j + 40 + q];
        int s6 = csr_src[j + 48 + q];
        int s7 = csr_src[j + 56 + q];
        uint4 w0 = *(const uint4*)(yh + (size_t)s0 * 64 + r * 8);
        uint4 w1 = *(const uint4*)(yh + (size_t)s1 * 64 + r * 8);
        uint4 w2 = *(const uint4*)(yh + (size_t)s2 * 64 + r * 8);
        uint4 w3 = *(const uint4*)(yh + (size_t)s3 * 64 + r * 8);
        uint4 w4 = *(const uint4*)(yh + (size_t)s4 * 64 + r * 8);
        uint4 w5 = *(const uint4*)(yh + (size_t)s5 * 64 + r * 8);
        uint4 w6 = *(const uint4*)(yh + (size_t)s6 * 64 + r * 8);
        uint4 w7 = *(const uint4*)(yh + (size_t)s7 * 64 + r * 8);
        hacc16(A, B, w0); hacc16(A, B, w1); hacc16(A, B, w2); hacc16(A, B, w3);
        hacc16(A, B, w4); hacc16(A, B, w5); hacc16(A, B, w6); hacc16(A, B, w7);
    }
#pragma unroll
    for (int m = 0; m < 8; m++) {
        int e = j + 8 * m + q;
        if (e < end) {
            int s = csr_src[e];
            uint4 w = *(const uint4*)(yh + (size_t)s * 64 + r * 8);
            hacc16(A, B, w);
        }
    }
#pragma unroll
    for (int o = 8; o <= 32; o <<= 1) {
        A.x += __shfl_xor(A.x, o); A.y += __shfl_xor(A.y, o);
        A.z += __shfl_xor(A.z, o); A.w += __shfl_xor(A.w, o);
        B.x += __shfl_xor(B.x, o); B.y += __shfl_xor(B.y, o);
        B.z += __shfl_xor(B.z, o); B.w += __shfl_xor(B.w, o);
    }
    if (lane < 8) {
        uint4 w = *(const uint4*)(yh + (size_t)wid * 64 + r * 8);
        hacc16(A, B, w);
        *(float4*)(u + (size_t)wid * 64 + r * 8) = A;
        *(float4*)(u + (size_t)wid * 64 + r * 8 + 4) = B;
    }
}

// ---------- fused mlpAB (layers 0,1): fp32 u in, fp16 ynext out ----------
template <int LAYER>
__global__ __launch_bounds__(256) void mlpAB_kernel(const float* __restrict__ u,
                                                    const float* __restrict__ b1,
                                                    const float* __restrict__ W2,
                                                    const float* __restrict__ b2,
                                                    const float* __restrict__ W1n,
                                                    const float* __restrict__ Wm,
                                                    __half* __restrict__ ynext,
                                                    float* __restrict__ score,
                                                    int N, int totalWaves) {
    int lane = threadIdx.x & 63;
    int wid = (blockIdx.x * 256 + threadIdx.x) >> 6;
    float w2[64], w1[64];
#pragma unroll
    for (int k = 0; k < 64; k++) w2[k] = W2[k * 64 + lane];
#pragma unroll
    for (int k = 0; k < 64; k++) w1[k] = W1n[k * 64 + lane];
    float bb1 = b1[lane], bb2 = b2[lane], wm = Wm[LAYER * 64 + lane];

    int node = wid;
    float uin = (node < N) ? u[(size_t)node * 64 + lane] : 0.f;
    for (; node < N; node += totalWaves) {
        int nn = node + totalWaves;
        float unext = (nn < N) ? u[(size_t)nn * 64 + lane] : 0.f;
        float t = fmaxf(uin + bb1, 0.f);
        float a0 = 0.f, a1 = 0.f, a2 = 0.f, a3 = 0.f;
#pragma unroll
        for (int k = 0; k < 64; k += 4) {
            a0 = fmaf(rl(t, k + 0), w2[k + 0], a0);
            a1 = fmaf(rl(t, k + 1), w2[k + 1], a1);
            a2 = fmaf(rl(t, k + 2), w2[k + 2], a2);
            a3 = fmaf(rl(t, k + 3), w2[k + 3], a3);
        }
        float h = fmaxf(bb2 + ((a0 + a1) + (a2 + a3)), 0.f);
        float p = h * wm;
#pragma unroll
        for (int o = 32; o >= 1; o >>= 1) p += __shfl_xor(p, o);
        if (lane == 0) {
            if (LAYER == 0) score[node] = p;
            else score[node] += p;
        }
        float y0 = 0.f, y1 = 0.f, y2 = 0.f, y3 = 0.f;
#pragma unroll
        for (int k = 0; k < 64; k += 4) {
            y0 = fmaf(rl(h, k + 0), w1[k + 0], y0);
            y1 = fmaf(rl(h, k + 1), w1[k + 1], y1);
            y2 = fmaf(rl(h, k + 2), w1[k + 2], y2);
            y3 = fmaf(rl(h, k + 3), w1[k + 3], y3);
        }
        ynext[(size_t)node * 64 + lane] = __float2half((y0 + y1) + (y2 + y3));
        uin = unext;
    }
}

// ---------- mlpA2 (layer 2) ----------
__global__ __launch_bounds__(256) void mlpA2_kernel(const float* __restrict__ u,
                                                    const float* __restrict__ b1,
                                                    const float* __restrict__ W2,
                                                    const float* __restrict__ b2,
                                                    const float* __restrict__ Wm,
                                                    float* __restrict__ score,
                                                    int N, int totalWaves) {
    int lane = threadIdx.x & 63;
    int wid = (blockIdx.x * 256 + threadIdx.x) >> 6;
    float w2[64];
#pragma unroll
    for (int k = 0; k < 64; k++) w2[k] = W2[k * 64 + lane];
    float bb1 = b1[lane], bb2 = b2[lane], wm = Wm[2 * 64 + lane];

    int node = wid;
    float uin = (node < N) ? u[(size_t)node * 64 + lane] : 0.f;
    for (; node < N; node += totalWaves) {
        int nn = node + totalWaves;
        float unext = (nn < N) ? u[(size_t)nn * 64 + lane] : 0.f;
        float t = fmaxf(uin + bb1, 0.f);
        float a0 = 0.f, a1 = 0.f, a2 = 0.f, a3 = 0.f;
#pragma unroll
        for (int k = 0; k < 64; k += 4) {
            a0 = fmaf(rl(t, k + 0), w2[k + 0], a0);
            a1 = fmaf(rl(t, k + 1), w2[k + 1], a1);
            a2 = fmaf(rl(t, k + 2), w2[k + 2], a2);
            a3 = fmaf(rl(t, k + 3), w2[k + 3], a3);
        }
        float h = bb2 + ((a0 + a1) + (a2 + a3));
        float p = h * wm;
#pragma unroll
        for (int o = 32; o >= 1; o >>= 1) p += __shfl_xor(p, o);
        if (lane == 0) score[node] += p;
        uin = unext;
    }
}

// ---------- edge softmax + new_score ----------
__global__ __launch_bounds__(256) void edge_softmax_kernel(const float* __restrict__ score,
                                                           const int* __restrict__ rowptr,
                                                           const int* __restrict__ csr_src,
                                                           const float* __restrict__ bm,
                                                           float* __restrict__ nsf, int N) {
    int wid = (blockIdx.x * blockDim.x + threadIdx.x) >> 6;
    int lane = threadIdx.x & 63;
    if (wid >= N) return;
    float b = bm[0];
    float sd = score[wid] + b;
    int start = rowptr[wid];
    int end = rowptr[wid + 1];
    bool has0 = (start + lane < end);
    float ss0 = 0.f;
    float m = -INFINITY;
    if (has0) {
        ss0 = score[csr_src[start + lane]] + b;
        m = ss0 * sd;
    }
    for (int j = start + 64 + lane; j < end; j += 64) {
        float ss = score[csr_src[j]] + b;
        m = fmaxf(m, ss * sd);
    }
#pragma unroll
    for (int o = 32; o >= 1; o >>= 1) m = fmaxf(m, __shfl_xor(m, o));
    float se = 0.f, swe = 0.f;
    if (m > -INFINITY) {
        if (has0) {
            float e0 = expf(ss0 * sd - m);
            se += e0;
            swe += ss0 * e0;
        }
        for (int j = start + 64 + lane; j < end; j += 64) {
            float ss = score[csr_src[j]] + b;
            float e = expf(ss * sd - m);
            se += e;
            swe += ss * e;
        }
#pragma unroll
        for (int o = 32; o >= 1; o >>= 1) {
            se += __shfl_xor(se, o);
            swe += __shfl_xor(swe, o);
        }
    }
    float ns = (se > 0.f) ? (swe / se) : 0.f;
    if (lane == 0) nsf[wid] = sd + ns;
}

// ---------- fused graph-segment softmax: one block per graph ----------
__global__ __launch_bounds__(256) void graph_softmax_kernel(const float* __restrict__ nsf,
                                                            const int* __restrict__ batch,
                                                            float* __restrict__ out, int N) {
    int g = blockIdx.x;
    int tid = threadIdx.x;
    int lo = 0, hi = N;
    while (lo < hi) { int mid = (lo + hi) >> 1; if (batch[mid] < g) lo = mid + 1; else hi = mid; }
    int s0 = lo;
    hi = N;
    while (lo < hi) { int mid = (lo + hi) >> 1; if (batch[mid] < g + 1) lo = mid + 1; else hi = mid; }
    int s1 = lo;

    __shared__ float red[4];
    __shared__ float bval;
    float m = -INFINITY;
    for (int i = s0 + tid; i < s1; i += 256) m = fmaxf(m, nsf[i]);
#pragma unroll
    for (int o = 32; o >= 1; o >>= 1) m = fmaxf(m, __shfl_xor(m, o));
    if ((tid & 63) == 0) red[tid >> 6] = m;
    __syncthreads();
    if (tid == 0) bval = fmaxf(fmaxf(red[0], red[1]), fmaxf(red[2], red[3]));
    __syncthreads();
    float bmx = bval;
    float s = 0.f;
    for (int i = s0 + tid; i < s1; i += 256) {
        float e = expf(nsf[i] - bmx);
        out[i] = e;
        s += e;
    }
#pragma unroll
    for (int o = 32; o >= 1; o >>= 1) s += __shfl_xor(s, o);
    __syncthreads();
    if ((tid & 63) == 0) red[tid >> 6] = s;
    __syncthreads();
    if (tid == 0) bval = red[0] + red[1] + red[2] + red[3];
    __syncthreads();
    float inv = 1.f / bval;
    for (int i = s0 + tid; i < s1; i += 256) out[i] *= inv;
}

extern "C" void kernel_launch(void* const* d_in, const int* in_sizes, int n_in,
                              void* d_out, int out_size, void* d_ws, size_t ws_size,
                              hipStream_t stream) {
    const int N = N_NODES, E = N_EDGES;

    const float* x = (const float*)d_in[0];
    const int* ei = (const int*)d_in[1];
    const int* batch = (const int*)d_in[2];
    const float* W1a[3] = {(const float*)d_in[3], (const float*)d_in[7], (const float*)d_in[11]};
    const float* b1a[3] = {(const float*)d_in[4], (const float*)d_in[8], (const float*)d_in[12]};
    const float* W2a[3] = {(const float*)d_in[5], (const float*)d_in[9], (const float*)d_in[13]};
    const float* b2a[3] = {(const float*)d_in[6], (const float*)d_in[10], (const float*)d_in[14]};
    const float* Wm = (const float*)d_in[15];
    const float* bm = (const float*)d_in[16];
    float* out = (float*)d_out;

    const int* srcp = ei;
    const int* dstp = ei + E;

    // workspace layout (~59 MB; csrc_chunk aliases ubuf — ubuf first written after gatherfill)
    float* ubuf = (float*)d_ws;                 // N*64 f32 (aliases csrc_chunk)
    int* csrc_chunk = (int*)ubuf;               // E ints (6.4MB of ubuf's 12.8MB)
    __half* yA = (__half*)(ubuf + (size_t)N * 64);  // N*64 f16
    __half* yB = yA + (size_t)N * 64;               // N*64 f16
    float* score = (float*)(yB + (size_t)N * 64);   // N
    float* nsf = score + N;                     // N
    int* deg = (int*)(nsf + N);                 // N
    int* rowptr = deg + N;                      // N+1
    int* part = rowptr + N + 1;                 // 64
    int* csr_src = part + 64;                   // E
    unsigned short* locs = (unsigned short*)(csr_src + E);        // CHUNKS*(N+1) u16
    unsigned short* base = locs + (size_t)CHUNKS * NP1;           // CHUNKS*N u16

    histsort_kernel<<<CHUNKS, 1024, 0, stream>>>(srcp, dstp, csrc_chunk, locs);

    const int nbScan = (N + 1023) / 1024;  // 49
    base_scan1_kernel<<<nbScan, 1024, 0, stream>>>(locs, base, deg, part, N);
    scan3_kernel<<<nbScan, 1024, 0, stream>>>(deg, part, rowptr, N, nbScan);

    const int gfBlocks = 8 * ((N / 8 + 3) / 4);  // 12504
    gatherfill_kernel<<<gfBlocks, 256, 0, stream>>>(csrc_chunk, locs, base, rowptr, csr_src);

    const int gw = 4096;
    gemm0_kernel<<<1024, 256, 0, stream>>>(x, W1a[0], yA, N, gw);

    int aggBlocks = (N + 3) / 4;  // one wave per node

    agg_kernel<<<aggBlocks, 256, 0, stream>>>(yA, rowptr, csr_src, ubuf, N);
    mlpAB_kernel<0><<<1024, 256, 0, stream>>>(ubuf, b1a[0], W2a[0], b2a[0], W1a[1], Wm, yB, score, N, gw);

    agg_kernel<<<aggBlocks, 256, 0, stream>>>(yB, rowptr, csr_src, ubuf, N);
    mlpAB_kernel<1><<<1024, 256, 0, stream>>>(ubuf, b1a[1], W2a[1], b2a[1], W1a[2], Wm, yA, score, N, gw);

    agg_kernel<<<aggBlocks, 256, 0, stream>>>(yA, rowptr, csr_src, ubuf, N);
    mlpA2_kernel<<<1024, 256, 0, stream>>>(ubuf, b1a[2], W2a[2], b2a[2], Wm, score, N, gw);

    edge_softmax_kernel<<<(N + 3) / 4, 256, 0, stream>>>(score, rowptr, csr_src, bm, nsf, N);

    graph_softmax_kernel<<<N_GRAPH, 256, 0, stream>>>(nsf, batch, out, N);
}

// Round 15
// 341.957 us; speedup vs baseline: 1.0894x; 1.0206x over previous
//
#include <hip/hip_runtime.h>
#include <hip/hip_fp16.h>
#include <math.h>

#define N_NODES 50000
#define N_EDGES 1600000
#define N_GRAPH 500
#define CHUNKS 128
#define EPC (N_EDGES / CHUNKS)  // 12500 edges per chunk
#define NP1 (N_NODES + 1)
#define NIT ((EPC + 1023) / 1024)  // 13 edge-iterations per histsort thread
#define HALF_N (N_NODES / 2)       // 25000 nodes per half-range
#define HNP1 (HALF_N + 1)

// ---------- helpers ----------
__device__ __forceinline__ float rl(float v, int k) {
    return __int_as_float(__builtin_amdgcn_readlane(__float_as_int(v), k));
}
// accumulate 8 fp16 (uint4) into two float4
__device__ __forceinline__ void hacc16(float4& A, float4& B, uint4 w) {
    float2 f0 = __half22float2(*reinterpret_cast<__half2*>(&w.x));
    float2 f1 = __half22float2(*reinterpret_cast<__half2*>(&w.y));
    float2 f2 = __half22float2(*reinterpret_cast<__half2*>(&w.z));
    float2 f3 = __half22float2(*reinterpret_cast<__half2*>(&w.w));
    A.x += f0.x; A.y += f0.y; A.z += f1.x; A.w += f1.y;
    B.x += f2.x; B.y += f2.y; B.z += f3.x; B.w += f3.y;
}

// ---------- histsort (half-range split): block = (chunk c, half h).
// 50KB LDS histogram of 25000 nodes; reads full chunk, processes its half.
// Emits locs[(c,h)][ld] (u16 exclusive offsets, sentinel=count at ld=HALF_N)
// and csrc_chunk[(c,h)] dst-sorted sub-array. No global atomics.
__global__ __launch_bounds__(1024) void histsort_kernel(const int* __restrict__ src,
                                                        const int* __restrict__ dst,
                                                        int* __restrict__ csrc_chunk,
                                                        unsigned short* __restrict__ locs) {
    __shared__ unsigned packed[HALF_N / 2];  // 50 KB
    __shared__ unsigned aux[1024];
    const int c = blockIdx.x >> 1;
    const int h = blockIdx.x & 1;
    const int lo = h * HALF_N;
    const int s0 = c * EPC;
    const int tid = threadIdx.x;

    for (int i = tid; i < HALF_N / 2; i += 1024) packed[i] = 0;
    __syncthreads();

    unsigned short lrv[NIT];
#pragma unroll
    for (int it = 0; it < NIT; it++) {
        int e = s0 + it * 1024 + tid;
        if (e < s0 + EPC) {
            int d = dst[e];
            int ld = d - lo;
            if (ld >= 0 && ld < HALF_N) {
                int sh = (ld & 1) * 16;
                unsigned old = atomicAdd(&packed[ld >> 1], 1u << sh);
                lrv[it] = (unsigned short)((old >> sh) & 0xffffu);
            }
        }
    }
    __syncthreads();

    // in-place exclusive scan over 25000 16-bit counters (prefix <= 12500 fits u16)
    const int W = 13;  // 13*1024 >= 12500 words
    int w0 = tid * W;
    int w1 = min(w0 + W, HALF_N / 2);
    unsigned run = 0;
    for (int i = w0; i < w1; i++) {
        unsigned v = packed[i];
        unsigned plo = v & 0xffffu, phi = v >> 16;
        packed[i] = run | ((run + plo) << 16);
        run += plo + phi;
    }
    aux[tid] = run;
    __syncthreads();
    for (int off = 1; off < 1024; off <<= 1) {
        unsigned t = (tid >= off) ? aux[tid - off] : 0;
        __syncthreads();
        aux[tid] += t;
        __syncthreads();
    }
    unsigned b0 = (tid == 0) ? 0 : aux[tid - 1];
    if (b0) {
        unsigned addv = b0 | (b0 << 16);
        for (int i = w0; i < w1; i++) packed[i] += addv;
    }
    __syncthreads();
    unsigned total = aux[1023];  // edges of this chunk falling in this half

    // scatter this (chunk, half)'s edges into dst-sorted local order
    int* outc = csrc_chunk + (size_t)(c * 2 + h) * EPC;
#pragma unroll
    for (int it = 0; it < NIT; it++) {
        int e = s0 + it * 1024 + tid;
        if (e < s0 + EPC) {
            int d = dst[e];
            int ld = d - lo;
            if (ld >= 0 && ld < HALF_N) {
                unsigned pw = packed[ld >> 1];
                unsigned loc = (ld & 1) ? (pw >> 16) : (pw & 0xffffu);
                outc[loc + lrv[it]] = src[e];
            }
        }
    }
    // emit loc per local node (+ sentinel = total)
    unsigned short* lc = locs + (size_t)(c * 2 + h) * HNP1;
    for (int ld = tid; ld <= HALF_N; ld += 1024) {
        unsigned short v;
        if (ld == HALF_N) {
            v = (unsigned short)total;
        } else {
            unsigned pw = packed[ld >> 1];
            v = (unsigned short)((ld & 1) ? (pw >> 16) : (pw & 0xffffu));
        }
        lc[ld] = v;
    }
}

// ---------- base + scan1 fused ----------
__global__ __launch_bounds__(1024) void base_scan1_kernel(const unsigned short* __restrict__ locs,
                                                          unsigned short* __restrict__ base,
                                                          int* __restrict__ deg,
                                                          int* __restrict__ part, int N) {
    int d = blockIdx.x * 1024 + threadIdx.x;
    int run = 0;
    if (d < N) {
        int h = (d >= HALF_N) ? 1 : 0;
        int ld = d - h * HALF_N;
#pragma unroll 8
        for (int c = 0; c < CHUNKS; c++) {
            const unsigned short* lc = locs + (size_t)(c * 2 + h) * HNP1;
            int l0 = lc[ld];
            int l1 = lc[ld + 1];
            base[(size_t)c * N + d] = (unsigned short)run;
            run += l1 - l0;
        }
        deg[d] = run;
    }
    int v = run;
#pragma unroll
    for (int o = 32; o >= 1; o >>= 1) v += __shfl_xor(v, o);
    __shared__ int red[16];
    if ((threadIdx.x & 63) == 0) red[threadIdx.x >> 6] = v;
    __syncthreads();
    if (threadIdx.x == 0) {
        int s = 0;
#pragma unroll
        for (int k = 0; k < 16; k++) s += red[k];
        part[blockIdx.x] = s;
    }
}

// ---------- scan3 with self-computed block offset (no scan2 launch) ----------
__global__ __launch_bounds__(1024) void scan3_kernel(const int* __restrict__ deg,
                                                     const int* __restrict__ part,
                                                     int* __restrict__ rowptr, int N, int nb) {
    __shared__ int blockOff;
    __shared__ int wsum[16];
    int lane = threadIdx.x & 63;
    int w = threadIdx.x >> 6;
    if (threadIdx.x < 64) {
        int pv = (lane < nb && lane < (int)blockIdx.x) ? part[lane] : 0;
#pragma unroll
        for (int o = 32; o >= 1; o >>= 1) pv += __shfl_xor(pv, o);
        if (lane == 0) blockOff = pv;
    }
    int i = blockIdx.x * 1024 + threadIdx.x;
    int v = (i < N) ? deg[i] : 0;
    int inc = v;
#pragma unroll
    for (int o = 1; o < 64; o <<= 1) {
        int t = __shfl_up(inc, o);
        if (lane >= o) inc += t;
    }
    if (lane == 63) wsum[w] = inc;
    __syncthreads();
    if (threadIdx.x < 16) {
        int x = wsum[threadIdx.x];
        int xo = x;
#pragma unroll
        for (int o = 1; o < 16; o <<= 1) {
            int t = __shfl_up(x, o);
            if ((int)threadIdx.x >= o) x += t;
        }
        wsum[threadIdx.x] = x - xo;
    }
    __syncthreads();
    int b = blockOff + wsum[w];
    if (i < N) {
        rowptr[i] = b + inc - v;
        if (i == N - 1) rowptr[N] = b + inc;
    }
}

// ---------- gatherfill: one wave per node, lane covers 2 chunks ----------
__global__ __launch_bounds__(256) void gatherfill_kernel(const int* __restrict__ csrc_chunk,
                                                         const unsigned short* __restrict__ locs,
                                                         const unsigned short* __restrict__ base,
                                                         const int* __restrict__ rowptr,
                                                         int* __restrict__ csr_src) {
    const int perXcd = N_NODES / 8;  // 6250
    int xcd = blockIdx.x & 7;
    int idx = (blockIdx.x >> 3) * 4 + (threadIdx.x >> 6);
    if (idx >= perXcd) return;
    int wid = xcd * perXcd + idx;
    int lane = threadIdx.x & 63;
    int h = (wid >= HALF_N) ? 1 : 0;
    int ld = wid - h * HALF_N;
    int rp = rowptr[wid];
#pragma unroll
    for (int cc = 0; cc < 2; cc++) {
        int c = lane + cc * 64;
        const unsigned short* lc = locs + (size_t)(c * 2 + h) * HNP1;
        int l0 = lc[ld];
        int l1 = lc[ld + 1];
        int cnt = l1 - l0;
        int ob = rp + (int)base[(size_t)c * N_NODES + wid];
        const int* in = csrc_chunk + (size_t)(c * 2 + h) * EPC + l0;
        for (int i = 0; i < cnt; i++) csr_src[ob + i] = in[i];
    }
}

// ---------- gemm0: y0 = x @ W1_0, both K-halves in registers, fp16 store ----------
__global__ __launch_bounds__(256) void gemm0_kernel(const float* __restrict__ x,
                                                    const float* __restrict__ W1,
                                                    __half* __restrict__ y0,
                                                    int N, int totalWaves) {
    int lane = threadIdx.x & 63;
    int wid = (blockIdx.x * 256 + threadIdx.x) >> 6;
    float wA[64], wB[64];
#pragma unroll
    for (int k = 0; k < 64; k++) wA[k] = W1[k * 64 + lane];
#pragma unroll
    for (int k = 0; k < 64; k++) wB[k] = W1[(64 + k) * 64 + lane];
    for (int node = wid; node < N; node += totalWaves) {
        float xa = x[(size_t)node * 128 + lane];
        float xb = x[(size_t)node * 128 + 64 + lane];
        float a0 = 0.f, a1 = 0.f, a2 = 0.f, a3 = 0.f;
#pragma unroll
        for (int k = 0; k < 64; k += 4) {
            a0 = fmaf(rl(xa, k + 0), wA[k + 0], a0);
            a1 = fmaf(rl(xa, k + 1), wA[k + 1], a1);
            a2 = fmaf(rl(xa, k + 2), wA[k + 2], a2);
            a3 = fmaf(rl(xa, k + 3), wA[k + 3], a3);
        }
#pragma unroll
        for (int k = 0; k < 64; k += 4) {
            a0 = fmaf(rl(xb, k + 0), wB[k + 0], a0);
            a1 = fmaf(rl(xb, k + 1), wB[k + 1], a1);
            a2 = fmaf(rl(xb, k + 2), wB[k + 2], a2);
            a3 = fmaf(rl(xb, k + 3), wB[k + 3], a3);
        }
        y0[(size_t)node * 64 + lane] = __float2half((a0 + a1) + (a2 + a3));
    }
}

// ---------- aggregation on fp16 y: uint4 loads, 8 edge slots, fp32 accum ----------
__global__ __launch_bounds__(256) void agg_kernel(const __half* __restrict__ yh,
                                                  const int* __restrict__ rowptr,
                                                  const int* __restrict__ csr_src,
                                                  float* __restrict__ u, int N) {
    int wid = (blockIdx.x * 256 + threadIdx.x) >> 6;
    int lane = threadIdx.x & 63;
    if (wid >= N) return;
    int q = lane >> 3;  // edge slot 0..7
    int r = lane & 7;   // feature oct 0..7 (8 halves = 16B each)
    int start = rowptr[wid];
    int end = rowptr[wid + 1];
    float4 A = make_float4(0.f, 0.f, 0.f, 0.f);
    float4 B = make_float4(0.f, 0.f, 0.f, 0.f);
    int j = start;
    for (; j + 64 <= end; j += 64) {
        int s0 = csr_src[j + q];
        int s1 = csr_src[j + 8 + q];
        int s2 = csr_src[j + 16 + q];
        int s3 = csr_src[j + 24 + q];
        int s4 = csr_src[j + 32 + q];
        int s5 = csr_src[j + 40 + q];
        int s6 = csr_src[j + 48 + q];
        int s7 = csr_src[j + 56 + q];
        uint4 w0 = *(const uint4*)(yh + (size_t)s0 * 64 + r * 8);
        uint4 w1 = *(const uint4*)(yh + (size_t)s1 * 64 + r * 8);
        uint4 w2 = *(const uint4*)(yh + (size_t)s2 * 64 + r * 8);
        uint4 w3 = *(const uint4*)(yh + (size_t)s3 * 64 + r * 8);
        uint4 w4 = *(const uint4*)(yh + (size_t)s4 * 64 + r * 8);
        uint4 w5 = *(const uint4*)(yh + (size_t)s5 * 64 + r * 8);
        uint4 w6 = *(const uint4*)(yh + (size_t)s6 * 64 + r * 8);
        uint4 w7 = *(const uint4*)(yh + (size_t)s7 * 64 + r * 8);
        hacc16(A, B, w0); hacc16(A, B, w1); hacc16(A, B, w2); hacc16(A, B, w3);
        hacc16(A, B, w4); hacc16(A, B, w5); hacc16(A, B, w6); hacc16(A, B, w7);
    }
#pragma unroll
    for (int m = 0; m < 8; m++) {
        int e = j + 8 * m + q;
        if (e < end) {
            int s = csr_src[e];
            uint4 w = *(const uint4*)(yh + (size_t)s * 64 + r * 8);
            hacc16(A, B, w);
        }
    }
#pragma unroll
    for (int o = 8; o <= 32; o <<= 1) {
        A.x += __shfl_xor(A.x, o); A.y += __shfl_xor(A.y, o);
        A.z += __shfl_xor(A.z, o); A.w += __shfl_xor(A.w, o);
        B.x += __shfl_xor(B.x, o); B.y += __shfl_xor(B.y, o);
        B.z += __shfl_xor(B.z, o); B.w += __shfl_xor(B.w, o);
    }
    if (lane < 8) {
        uint4 w = *(const uint4*)(yh + (size_t)wid * 64 + r * 8);
        hacc16(A, B, w);
        *(float4*)(u + (size_t)wid * 64 + r * 8) = A;
        *(float4*)(u + (size_t)wid * 64 + r * 8 + 4) = B;
    }
}

// ---------- fused mlpAB (layers 0,1): fp32 u in, fp16 ynext out ----------
template <int LAYER>
__global__ __launch_bounds__(256) void mlpAB_kernel(const float* __restrict__ u,
                                                    const float* __restrict__ b1,
                                                    const float* __restrict__ W2,
                                                    const float* __restrict__ b2,
                                                    const float* __restrict__ W1n,
                                                    const float* __restrict__ Wm,
                                                    __half* __restrict__ ynext,
                                                    float* __restrict__ score,
                                                    int N, int totalWaves) {
    int lane = threadIdx.x & 63;
    int wid = (blockIdx.x * 256 + threadIdx.x) >> 6;
    float w2[64], w1[64];
#pragma unroll
    for (int k = 0; k < 64; k++) w2[k] = W2[k * 64 + lane];
#pragma unroll
    for (int k = 0; k < 64; k++) w1[k] = W1n[k * 64 + lane];
    float bb1 = b1[lane], bb2 = b2[lane], wm = Wm[LAYER * 64 + lane];

    int node = wid;
    float uin = (node < N) ? u[(size_t)node * 64 + lane] : 0.f;
    for (; node < N; node += totalWaves) {
        int nn = node + totalWaves;
        float unext = (nn < N) ? u[(size_t)nn * 64 + lane] : 0.f;
        float t = fmaxf(uin + bb1, 0.f);
        float a0 = 0.f, a1 = 0.f, a2 = 0.f, a3 = 0.f;
#pragma unroll
        for (int k = 0; k < 64; k += 4) {
            a0 = fmaf(rl(t, k + 0), w2[k + 0], a0);
            a1 = fmaf(rl(t, k + 1), w2[k + 1], a1);
            a2 = fmaf(rl(t, k + 2), w2[k + 2], a2);
            a3 = fmaf(rl(t, k + 3), w2[k + 3], a3);
        }
        float h = fmaxf(bb2 + ((a0 + a1) + (a2 + a3)), 0.f);
        float p = h * wm;
#pragma unroll
        for (int o = 32; o >= 1; o >>= 1) p += __shfl_xor(p, o);
        if (lane == 0) {
            if (LAYER == 0) score[node] = p;
            else score[node] += p;
        }
        float y0 = 0.f, y1 = 0.f, y2 = 0.f, y3 = 0.f;
#pragma unroll
        for (int k = 0; k < 64; k += 4) {
            y0 = fmaf(rl(h, k + 0), w1[k + 0], y0);
            y1 = fmaf(rl(h, k + 1), w1[k + 1], y1);
            y2 = fmaf(rl(h, k + 2), w1[k + 2], y2);
            y3 = fmaf(rl(h, k + 3), w1[k + 3], y3);
        }
        ynext[(size_t)node * 64 + lane] = __float2half((y0 + y1) + (y2 + y3));
        uin = unext;
    }
}

// ---------- mlpA2 (layer 2) ----------
__global__ __launch_bounds__(256) void mlpA2_kernel(const float* __restrict__ u,
                                                    const float* __restrict__ b1,
                                                    const float* __restrict__ W2,
                                                    const float* __restrict__ b2,
                                                    const float* __restrict__ Wm,
                                                    float* __restrict__ score,
                                                    int N, int totalWaves) {
    int lane = threadIdx.x & 63;
    int wid = (blockIdx.x * 256 + threadIdx.x) >> 6;
    float w2[64];
#pragma unroll
    for (int k = 0; k < 64; k++) w2[k] = W2[k * 64 + lane];
    float bb1 = b1[lane], bb2 = b2[lane], wm = Wm[2 * 64 + lane];

    int node = wid;
    float uin = (node < N) ? u[(size_t)node * 64 + lane] : 0.f;
    for (; node < N; node += totalWaves) {
        int nn = node + totalWaves;
        float unext = (nn < N) ? u[(size_t)nn * 64 + lane] : 0.f;
        float t = fmaxf(uin + bb1, 0.f);
        float a0 = 0.f, a1 = 0.f, a2 = 0.f, a3 = 0.f;
#pragma unroll
        for (int k = 0; k < 64; k += 4) {
            a0 = fmaf(rl(t, k + 0), w2[k + 0], a0);
            a1 = fmaf(rl(t, k + 1), w2[k + 1], a1);
            a2 = fmaf(rl(t, k + 2), w2[k + 2], a2);
            a3 = fmaf(rl(t, k + 3), w2[k + 3], a3);
        }
        float h = bb2 + ((a0 + a1) + (a2 + a3));
        float p = h * wm;
#pragma unroll
        for (int o = 32; o >= 1; o >>= 1) p += __shfl_xor(p, o);
        if (lane == 0) score[node] += p;
        uin = unext;
    }
}

// ---------- edge softmax + new_score ----------
__global__ __launch_bounds__(256) void edge_softmax_kernel(const float* __restrict__ score,
                                                           const int* __restrict__ rowptr,
                                                           const int* __restrict__ csr_src,
                                                           const float* __restrict__ bm,
                                                           float* __restrict__ nsf, int N) {
    int wid = (blockIdx.x * blockDim.x + threadIdx.x) >> 6;
    int lane = threadIdx.x & 63;
    if (wid >= N) return;
    float b = bm[0];
    float sd = score[wid] + b;
    int start = rowptr[wid];
    int end = rowptr[wid + 1];
    bool has0 = (start + lane < end);
    float ss0 = 0.f;
    float m = -INFINITY;
    if (has0) {
        ss0 = score[csr_src[start + lane]] + b;
        m = ss0 * sd;
    }
    for (int j = start + 64 + lane; j < end; j += 64) {
        float ss = score[csr_src[j]] + b;
        m = fmaxf(m, ss * sd);
    }
#pragma unroll
    for (int o = 32; o >= 1; o >>= 1) m = fmaxf(m, __shfl_xor(m, o));
    float se = 0.f, swe = 0.f;
    if (m > -INFINITY) {
        if (has0) {
            float e0 = expf(ss0 * sd - m);
            se += e0;
            swe += ss0 * e0;
        }
        for (int j = start + 64 + lane; j < end; j += 64) {
            float ss = score[csr_src[j]] + b;
            float e = expf(ss * sd - m);
            se += e;
            swe += ss * e;
        }
#pragma unroll
        for (int o = 32; o >= 1; o >>= 1) {
            se += __shfl_xor(se, o);
            swe += __shfl_xor(swe, o);
        }
    }
    float ns = (se > 0.f) ? (swe / se) : 0.f;
    if (lane == 0) nsf[wid] = sd + ns;
}

// ---------- fused graph-segment softmax: one block per graph ----------
__global__ __launch_bounds__(256) void graph_softmax_kernel(const float* __restrict__ nsf,
                                                            const int* __restrict__ batch,
                                                            float* __restrict__ out, int N) {
    int g = blockIdx.x;
    int tid = threadIdx.x;
    int lo = 0, hi = N;
    while (lo < hi) { int mid = (lo + hi) >> 1; if (batch[mid] < g) lo = mid + 1; else hi = mid; }
    int s0 = lo;
    hi = N;
    while (lo < hi) { int mid = (lo + hi) >> 1; if (batch[mid] < g + 1) lo = mid + 1; else hi = mid; }
    int s1 = lo;

    __shared__ float red[4];
    __shared__ float bval;
    float m = -INFINITY;
    for (int i = s0 + tid; i < s1; i += 256) m = fmaxf(m, nsf[i]);
#pragma unroll
    for (int o = 32; o >= 1; o >>= 1) m = fmaxf(m, __shfl_xor(m, o));
    if ((tid & 63) == 0) red[tid >> 6] = m;
    __syncthreads();
    if (tid == 0) bval = fmaxf(fmaxf(red[0], red[1]), fmaxf(red[2], red[3]));
    __syncthreads();
    float bmx = bval;
    float s = 0.f;
    for (int i = s0 + tid; i < s1; i += 256) {
        float e = expf(nsf[i] - bmx);
        out[i] = e;
        s += e;
    }
#pragma unroll
    for (int o = 32; o >= 1; o >>= 1) s += __shfl_xor(s, o);
    __syncthreads();
    if ((tid & 63) == 0) red[tid >> 6] = s;
    __syncthreads();
    if (tid == 0) bval = red[0] + red[1] + red[2] + red[3];
    __syncthreads();
    float inv = 1.f / bval;
    for (int i = s0 + tid; i < s1; i += 256) out[i] *= inv;
}

extern "C" void kernel_launch(void* const* d_in, const int* in_sizes, int n_in,
                              void* d_out, int out_size, void* d_ws, size_t ws_size,
                              hipStream_t stream) {
    const int N = N_NODES, E = N_EDGES;

    const float* x = (const float*)d_in[0];
    const int* ei = (const int*)d_in[1];
    const int* batch = (const int*)d_in[2];
    const float* W1a[3] = {(const float*)d_in[3], (const float*)d_in[7], (const float*)d_in[11]};
    const float* b1a[3] = {(const float*)d_in[4], (const float*)d_in[8], (const float*)d_in[12]};
    const float* W2a[3] = {(const float*)d_in[5], (const float*)d_in[9], (const float*)d_in[13]};
    const float* b2a[3] = {(const float*)d_in[6], (const float*)d_in[10], (const float*)d_in[14]};
    const float* Wm = (const float*)d_in[15];
    const float* bm = (const float*)d_in[16];
    float* out = (float*)d_out;

    const int* srcp = ei;
    const int* dstp = ei + E;

    // workspace layout (~59 MB; csrc_chunk aliases ubuf fully — 256 regions x EPC ints = 12.8MB)
    float* ubuf = (float*)d_ws;                 // N*64 f32 (aliases csrc_chunk)
    int* csrc_chunk = (int*)ubuf;               // 2*E ints = 12.8MB (= ubuf size)
    __half* yA = (__half*)(ubuf + (size_t)N * 64);  // N*64 f16
    __half* yB = yA + (size_t)N * 64;               // N*64 f16
    float* score = (float*)(yB + (size_t)N * 64);   // N
    float* nsf = score + N;                     // N
    int* deg = (int*)(nsf + N);                 // N
    int* rowptr = deg + N;                      // N+1
    int* part = rowptr + N + 1;                 // 64
    int* csr_src = part + 64;                   // E
    unsigned short* locs = (unsigned short*)(csr_src + E);        // 2*CHUNKS*HNP1 u16
    unsigned short* base = locs + (size_t)2 * CHUNKS * HNP1;      // CHUNKS*N u16

    histsort_kernel<<<CHUNKS * 2, 1024, 0, stream>>>(srcp, dstp, csrc_chunk, locs);

    const int nbScan = (N + 1023) / 1024;  // 49
    base_scan1_kernel<<<nbScan, 1024, 0, stream>>>(locs, base, deg, part, N);
    scan3_kernel<<<nbScan, 1024, 0, stream>>>(deg, part, rowptr, N, nbScan);

    const int gfBlocks = 8 * ((N / 8 + 3) / 4);  // 12504
    gatherfill_kernel<<<gfBlocks, 256, 0, stream>>>(csrc_chunk, locs, base, rowptr, csr_src);

    const int gw = 4096;
    gemm0_kernel<<<1024, 256, 0, stream>>>(x, W1a[0], yA, N, gw);

    int aggBlocks = (N + 3) / 4;  // one wave per node

    agg_kernel<<<aggBlocks, 256, 0, stream>>>(yA, rowptr, csr_src, ubuf, N);
    mlpAB_kernel<0><<<1024, 256, 0, stream>>>(ubuf, b1a[0], W2a[0], b2a[0], W1a[1], Wm, yB, score, N, gw);

    agg_kernel<<<aggBlocks, 256, 0, stream>>>(yB, rowptr, csr_src, ubuf, N);
    mlpAB_kernel<1><<<1024, 256, 0, stream>>>(ubuf, b1a[1], W2a[1], b2a[1], W1a[2], Wm, yA, score, N, gw);

    agg_kernel<<<aggBlocks, 256, 0, stream>>>(yA, rowptr, csr_src, ubuf, N);
    mlpA2_kernel<<<1024, 256, 0, stream>>>(ubuf, b1a[2], W2a[2], b2a[2], Wm, score, N, gw);

    edge_softmax_kernel<<<(N + 3) / 4, 256, 0, stream>>>(score, rowptr, csr_src, bm, nsf, N);

    graph_softmax_kernel<<<N_GRAPH, 256, 0, stream>>>(nsf, batch, out, N);
}

// Round 16
// 320.812 us; speedup vs baseline: 1.1612x; 1.0659x over previous
//
#include <hip/hip_runtime.h>
#include <hip/hip_fp16.h>
#include <math.h>

#define N_NODES 50000
#define N_EDGES 1600000
#define N_GRAPH 500
#define CHUNKS 128
#define EPC (N_EDGES / CHUNKS)  // 12500 edges per chunk
#define NP1 (N_NODES + 1)
#define NIT ((EPC + 1023) / 1024)  // 13 edge-iterations per histsort thread
#define HALF_N (N_NODES / 2)       // 25000 nodes per half-range
#define HNP1 (HALF_N + 1)

// ---------- helpers ----------
__device__ __forceinline__ float rl(float v, int k) {
    return __int_as_float(__builtin_amdgcn_readlane(__float_as_int(v), k));
}
// accumulate 8 fp16 (uint4) into two float4
__device__ __forceinline__ void hacc16(float4& A, float4& B, uint4 w) {
    float2 f0 = __half22float2(*reinterpret_cast<__half2*>(&w.x));
    float2 f1 = __half22float2(*reinterpret_cast<__half2*>(&w.y));
    float2 f2 = __half22float2(*reinterpret_cast<__half2*>(&w.z));
    float2 f3 = __half22float2(*reinterpret_cast<__half2*>(&w.w));
    A.x += f0.x; A.y += f0.y; A.z += f1.x; A.w += f1.y;
    B.x += f2.x; B.y += f2.y; B.z += f3.x; B.w += f3.y;
}

// ---------- histsort (half-range split): block = (chunk c, half h). ----------
__global__ __launch_bounds__(1024) void histsort_kernel(const int* __restrict__ src,
                                                        const int* __restrict__ dst,
                                                        int* __restrict__ csrc_chunk,
                                                        unsigned short* __restrict__ locs) {
    __shared__ unsigned packed[HALF_N / 2];  // 50 KB
    __shared__ unsigned aux[1024];
    const int c = blockIdx.x >> 1;
    const int h = blockIdx.x & 1;
    const int lo = h * HALF_N;
    const int s0 = c * EPC;
    const int tid = threadIdx.x;

    for (int i = tid; i < HALF_N / 2; i += 1024) packed[i] = 0;
    __syncthreads();

    unsigned short lrv[NIT];
#pragma unroll
    for (int it = 0; it < NIT; it++) {
        int e = s0 + it * 1024 + tid;
        if (e < s0 + EPC) {
            int d = dst[e];
            int ld = d - lo;
            if (ld >= 0 && ld < HALF_N) {
                int sh = (ld & 1) * 16;
                unsigned old = atomicAdd(&packed[ld >> 1], 1u << sh);
                lrv[it] = (unsigned short)((old >> sh) & 0xffffu);
            }
        }
    }
    __syncthreads();

    const int W = 13;
    int w0 = tid * W;
    int w1 = min(w0 + W, HALF_N / 2);
    unsigned run = 0;
    for (int i = w0; i < w1; i++) {
        unsigned v = packed[i];
        unsigned plo = v & 0xffffu, phi = v >> 16;
        packed[i] = run | ((run + plo) << 16);
        run += plo + phi;
    }
    aux[tid] = run;
    __syncthreads();
    for (int off = 1; off < 1024; off <<= 1) {
        unsigned t = (tid >= off) ? aux[tid - off] : 0;
        __syncthreads();
        aux[tid] += t;
        __syncthreads();
    }
    unsigned b0 = (tid == 0) ? 0 : aux[tid - 1];
    if (b0) {
        unsigned addv = b0 | (b0 << 16);
        for (int i = w0; i < w1; i++) packed[i] += addv;
    }
    __syncthreads();
    unsigned total = aux[1023];

    int* outc = csrc_chunk + (size_t)(c * 2 + h) * EPC;
#pragma unroll
    for (int it = 0; it < NIT; it++) {
        int e = s0 + it * 1024 + tid;
        if (e < s0 + EPC) {
            int d = dst[e];
            int ld = d - lo;
            if (ld >= 0 && ld < HALF_N) {
                unsigned pw = packed[ld >> 1];
                unsigned loc = (ld & 1) ? (pw >> 16) : (pw & 0xffffu);
                outc[loc + lrv[it]] = src[e];
            }
        }
    }
    unsigned short* lc = locs + (size_t)(c * 2 + h) * HNP1;
    for (int ld = tid; ld <= HALF_N; ld += 1024) {
        unsigned short v;
        if (ld == HALF_N) {
            v = (unsigned short)total;
        } else {
            unsigned pw = packed[ld >> 1];
            v = (unsigned short)((ld & 1) ? (pw >> 16) : (pw & 0xffffu));
        }
        lc[ld] = v;
    }
}

// ---------- base + scan1 fused ----------
__global__ __launch_bounds__(1024) void base_scan1_kernel(const unsigned short* __restrict__ locs,
                                                          unsigned short* __restrict__ base,
                                                          int* __restrict__ deg,
                                                          int* __restrict__ part, int N) {
    int d = blockIdx.x * 1024 + threadIdx.x;
    int run = 0;
    if (d < N) {
        int h = (d >= HALF_N) ? 1 : 0;
        int ld = d - h * HALF_N;
#pragma unroll 8
        for (int c = 0; c < CHUNKS; c++) {
            const unsigned short* lc = locs + (size_t)(c * 2 + h) * HNP1;
            int l0 = lc[ld];
            int l1 = lc[ld + 1];
            base[(size_t)c * N + d] = (unsigned short)run;
            run += l1 - l0;
        }
        deg[d] = run;
    }
    int v = run;
#pragma unroll
    for (int o = 32; o >= 1; o >>= 1) v += __shfl_xor(v, o);
    __shared__ int red[16];
    if ((threadIdx.x & 63) == 0) red[threadIdx.x >> 6] = v;
    __syncthreads();
    if (threadIdx.x == 0) {
        int s = 0;
#pragma unroll
        for (int k = 0; k < 16; k++) s += red[k];
        part[blockIdx.x] = s;
    }
}

// ---------- scan3 with self-computed block offset ----------
__global__ __launch_bounds__(1024) void scan3_kernel(const int* __restrict__ deg,
                                                     const int* __restrict__ part,
                                                     int* __restrict__ rowptr, int N, int nb) {
    __shared__ int blockOff;
    __shared__ int wsum[16];
    int lane = threadIdx.x & 63;
    int w = threadIdx.x >> 6;
    if (threadIdx.x < 64) {
        int pv = (lane < nb && lane < (int)blockIdx.x) ? part[lane] : 0;
#pragma unroll
        for (int o = 32; o >= 1; o >>= 1) pv += __shfl_xor(pv, o);
        if (lane == 0) blockOff = pv;
    }
    int i = blockIdx.x * 1024 + threadIdx.x;
    int v = (i < N) ? deg[i] : 0;
    int inc = v;
#pragma unroll
    for (int o = 1; o < 64; o <<= 1) {
        int t = __shfl_up(inc, o);
        if (lane >= o) inc += t;
    }
    if (lane == 63) wsum[w] = inc;
    __syncthreads();
    if (threadIdx.x < 16) {
        int x = wsum[threadIdx.x];
        int xo = x;
#pragma unroll
        for (int o = 1; o < 16; o <<= 1) {
            int t = __shfl_up(x, o);
            if ((int)threadIdx.x >= o) x += t;
        }
        wsum[threadIdx.x] = x - xo;
    }
    __syncthreads();
    int b = blockOff + wsum[w];
    if (i < N) {
        rowptr[i] = b + inc - v;
        if (i == N - 1) rowptr[N] = b + inc;
    }
}

// ---------- gatherfill: one wave per node, lane covers 2 chunks ----------
__global__ __launch_bounds__(256) void gatherfill_kernel(const int* __restrict__ csrc_chunk,
                                                         const unsigned short* __restrict__ locs,
                                                         const unsigned short* __restrict__ base,
                                                         const int* __restrict__ rowptr,
                                                         int* __restrict__ csr_src) {
    const int perXcd = N_NODES / 8;  // 6250
    int xcd = blockIdx.x & 7;
    int idx = (blockIdx.x >> 3) * 4 + (threadIdx.x >> 6);
    if (idx >= perXcd) return;
    int wid = xcd * perXcd + idx;
    int lane = threadIdx.x & 63;
    int h = (wid >= HALF_N) ? 1 : 0;
    int ld = wid - h * HALF_N;
    int rp = rowptr[wid];
#pragma unroll
    for (int cc = 0; cc < 2; cc++) {
        int c = lane + cc * 64;
        const unsigned short* lc = locs + (size_t)(c * 2 + h) * HNP1;
        int l0 = lc[ld];
        int l1 = lc[ld + 1];
        int cnt = l1 - l0;
        int ob = rp + (int)base[(size_t)c * N_NODES + wid];
        const int* in = csrc_chunk + (size_t)(c * 2 + h) * EPC + l0;
        for (int i = 0; i < cnt; i++) csr_src[ob + i] = in[i];
    }
}

// ---------- gemm0: y0 = x @ W1_0, both K-halves in registers, fp16 store ----------
__global__ __launch_bounds__(256) void gemm0_kernel(const float* __restrict__ x,
                                                    const float* __restrict__ W1,
                                                    __half* __restrict__ y0,
                                                    int N, int totalWaves) {
    int lane = threadIdx.x & 63;
    int wid = (blockIdx.x * 256 + threadIdx.x) >> 6;
    float wA[64], wB[64];
#pragma unroll
    for (int k = 0; k < 64; k++) wA[k] = W1[k * 64 + lane];
#pragma unroll
    for (int k = 0; k < 64; k++) wB[k] = W1[(64 + k) * 64 + lane];
    for (int node = wid; node < N; node += totalWaves) {
        float xa = x[(size_t)node * 128 + lane];
        float xb = x[(size_t)node * 128 + 64 + lane];
        float a0 = 0.f, a1 = 0.f, a2 = 0.f, a3 = 0.f;
#pragma unroll
        for (int k = 0; k < 64; k += 4) {
            a0 = fmaf(rl(xa, k + 0), wA[k + 0], a0);
            a1 = fmaf(rl(xa, k + 1), wA[k + 1], a1);
            a2 = fmaf(rl(xa, k + 2), wA[k + 2], a2);
            a3 = fmaf(rl(xa, k + 3), wA[k + 3], a3);
        }
#pragma unroll
        for (int k = 0; k < 64; k += 4) {
            a0 = fmaf(rl(xb, k + 0), wB[k + 0], a0);
            a1 = fmaf(rl(xb, k + 1), wB[k + 1], a1);
            a2 = fmaf(rl(xb, k + 2), wB[k + 2], a2);
            a3 = fmaf(rl(xb, k + 3), wB[k + 3], a3);
        }
        y0[(size_t)node * 64 + lane] = __float2half((a0 + a1) + (a2 + a3));
    }
}

// ---------- aggregation: half-wave per node, 4 edge slots x 8 feature lanes ----------
__global__ __launch_bounds__(256) void agg_kernel(const __half* __restrict__ yh,
                                                  const int* __restrict__ rowptr,
                                                  const int* __restrict__ csr_src,
                                                  float* __restrict__ u, int N) {
    int wv = (blockIdx.x * 256 + threadIdx.x) >> 6;
    int half = (threadIdx.x >> 5) & 1;
    int node = wv * 2 + half;
    if (node >= N) return;
    int lane = threadIdx.x & 31;  // lane within half-wave
    int q = lane >> 3;            // edge slot 0..3
    int r = lane & 7;             // feature oct 0..7 (16B)
    int start = rowptr[node];
    int end = rowptr[node + 1];
    float4 A = make_float4(0.f, 0.f, 0.f, 0.f);
    float4 B = make_float4(0.f, 0.f, 0.f, 0.f);
    int j = start;
    for (; j + 32 <= end; j += 32) {
        int s0 = csr_src[j + q];
        int s1 = csr_src[j + 4 + q];
        int s2 = csr_src[j + 8 + q];
        int s3 = csr_src[j + 12 + q];
        int s4 = csr_src[j + 16 + q];
        int s5 = csr_src[j + 20 + q];
        int s6 = csr_src[j + 24 + q];
        int s7 = csr_src[j + 28 + q];
        uint4 w0 = *(const uint4*)(yh + (size_t)s0 * 64 + r * 8);
        uint4 w1 = *(const uint4*)(yh + (size_t)s1 * 64 + r * 8);
        uint4 w2 = *(const uint4*)(yh + (size_t)s2 * 64 + r * 8);
        uint4 w3 = *(const uint4*)(yh + (size_t)s3 * 64 + r * 8);
        uint4 w4 = *(const uint4*)(yh + (size_t)s4 * 64 + r * 8);
        uint4 w5 = *(const uint4*)(yh + (size_t)s5 * 64 + r * 8);
        uint4 w6 = *(const uint4*)(yh + (size_t)s6 * 64 + r * 8);
        uint4 w7 = *(const uint4*)(yh + (size_t)s7 * 64 + r * 8);
        hacc16(A, B, w0); hacc16(A, B, w1); hacc16(A, B, w2); hacc16(A, B, w3);
        hacc16(A, B, w4); hacc16(A, B, w5); hacc16(A, B, w6); hacc16(A, B, w7);
    }
    // tail: < 32 edges, 8 predicated independent loads per lane
#pragma unroll
    for (int m = 0; m < 8; m++) {
        int e = j + 4 * m + q;
        if (e < end) {
            int s = csr_src[e];
            uint4 w = *(const uint4*)(yh + (size_t)s * 64 + r * 8);
            hacc16(A, B, w);
        }
    }
    // reduce over 4 slots (xor 8,16 stays within the 32-lane half)
#pragma unroll
    for (int o = 8; o <= 16; o <<= 1) {
        A.x += __shfl_xor(A.x, o); A.y += __shfl_xor(A.y, o);
        A.z += __shfl_xor(A.z, o); A.w += __shfl_xor(A.w, o);
        B.x += __shfl_xor(B.x, o); B.y += __shfl_xor(B.y, o);
        B.z += __shfl_xor(B.z, o); B.w += __shfl_xor(B.w, o);
    }
    if (lane < 8) {
        uint4 w = *(const uint4*)(yh + (size_t)node * 64 + r * 8);
        hacc16(A, B, w);
        *(float4*)(u + (size_t)node * 64 + r * 8) = A;
        *(float4*)(u + (size_t)node * 64 + r * 8 + 4) = B;
    }
}

// ---------- fused mlpAB (layers 0,1): fp32 u in, fp16 ynext out ----------
template <int LAYER>
__global__ __launch_bounds__(256) void mlpAB_kernel(const float* __restrict__ u,
                                                    const float* __restrict__ b1,
                                                    const float* __restrict__ W2,
                                                    const float* __restrict__ b2,
                                                    const float* __restrict__ W1n,
                                                    const float* __restrict__ Wm,
                                                    __half* __restrict__ ynext,
                                                    float* __restrict__ score,
                                                    int N, int totalWaves) {
    int lane = threadIdx.x & 63;
    int wid = (blockIdx.x * 256 + threadIdx.x) >> 6;
    float w2[64], w1[64];
#pragma unroll
    for (int k = 0; k < 64; k++) w2[k] = W2[k * 64 + lane];
#pragma unroll
    for (int k = 0; k < 64; k++) w1[k] = W1n[k * 64 + lane];
    float bb1 = b1[lane], bb2 = b2[lane], wm = Wm[LAYER * 64 + lane];

    int node = wid;
    float uin = (node < N) ? u[(size_t)node * 64 + lane] : 0.f;
    for (; node < N; node += totalWaves) {
        int nn = node + totalWaves;
        float unext = (nn < N) ? u[(size_t)nn * 64 + lane] : 0.f;
        float t = fmaxf(uin + bb1, 0.f);
        float a0 = 0.f, a1 = 0.f, a2 = 0.f, a3 = 0.f;
#pragma unroll
        for (int k = 0; k < 64; k += 4) {
            a0 = fmaf(rl(t, k + 0), w2[k + 0], a0);
            a1 = fmaf(rl(t, k + 1), w2[k + 1], a1);
            a2 = fmaf(rl(t, k + 2), w2[k + 2], a2);
            a3 = fmaf(rl(t, k + 3), w2[k + 3], a3);
        }
        float h = fmaxf(bb2 + ((a0 + a1) + (a2 + a3)), 0.f);
        float p = h * wm;
#pragma unroll
        for (int o = 32; o >= 1; o >>= 1) p += __shfl_xor(p, o);
        if (lane == 0) {
            if (LAYER == 0) score[node] = p;
            else score[node] += p;
        }
        float y0 = 0.f, y1 = 0.f, y2 = 0.f, y3 = 0.f;
#pragma unroll
        for (int k = 0; k < 64; k += 4) {
            y0 = fmaf(rl(h, k + 0), w1[k + 0], y0);
            y1 = fmaf(rl(h, k + 1), w1[k + 1], y1);
            y2 = fmaf(rl(h, k + 2), w1[k + 2], y2);
            y3 = fmaf(rl(h, k + 3), w1[k + 3], y3);
        }
        ynext[(size_t)node * 64 + lane] = __float2half((y0 + y1) + (y2 + y3));
        uin = unext;
    }
}

// ---------- mlpA2 (layer 2) ----------
__global__ __launch_bounds__(256) void mlpA2_kernel(const float* __restrict__ u,
                                                    const float* __restrict__ b1,
                                                    const float* __restrict__ W2,
                                                    const float* __restrict__ b2,
                                                    const float* __restrict__ Wm,
                                                    float* __restrict__ score,
                                                    int N, int totalWaves) {
    int lane = threadIdx.x & 63;
    int wid = (blockIdx.x * 256 + threadIdx.x) >> 6;
    float w2[64];
#pragma unroll
    for (int k = 0; k < 64; k++) w2[k] = W2[k * 64 + lane];
    float bb1 = b1[lane], bb2 = b2[lane], wm = Wm[2 * 64 + lane];

    int node = wid;
    float uin = (node < N) ? u[(size_t)node * 64 + lane] : 0.f;
    for (; node < N; node += totalWaves) {
        int nn = node + totalWaves;
        float unext = (nn < N) ? u[(size_t)nn * 64 + lane] : 0.f;
        float t = fmaxf(uin + bb1, 0.f);
        float a0 = 0.f, a1 = 0.f, a2 = 0.f, a3 = 0.f;
#pragma unroll
        for (int k = 0; k < 64; k += 4) {
            a0 = fmaf(rl(t, k + 0), w2[k + 0], a0);
            a1 = fmaf(rl(t, k + 1), w2[k + 1], a1);
            a2 = fmaf(rl(t, k + 2), w2[k + 2], a2);
            a3 = fmaf(rl(t, k + 3), w2[k + 3], a3);
        }
        float h = bb2 + ((a0 + a1) + (a2 + a3));
        float p = h * wm;
#pragma unroll
        for (int o = 32; o >= 1; o >>= 1) p += __shfl_xor(p, o);
        if (lane == 0) score[node] += p;
        uin = unext;
    }
}

// ---------- edge softmax + new_score ----------
__global__ __launch_bounds__(256) void edge_softmax_kernel(const float* __restrict__ score,
                                                           const int* __restrict__ rowptr,
                                                           const int* __restrict__ csr_src,
                                                           const float* __restrict__ bm,
                                                           float* __restrict__ nsf, int N) {
    int wid = (blockIdx.x * blockDim.x + threadIdx.x) >> 6;
    int lane = threadIdx.x & 63;
    if (wid >= N) return;
    float b = bm[0];
    float sd = score[wid] + b;
    int start = rowptr[wid];
    int end = rowptr[wid + 1];
    bool has0 = (start + lane < end);
    float ss0 = 0.f;
    float m = -INFINITY;
    if (has0) {
        ss0 = score[csr_src[start + lane]] + b;
        m = ss0 * sd;
    }
    for (int j = start + 64 + lane; j < end; j += 64) {
        float ss = score[csr_src[j]] + b;
        m = fmaxf(m, ss * sd);
    }
#pragma unroll
    for (int o = 32; o >= 1; o >>= 1) m = fmaxf(m, __shfl_xor(m, o));
    float se = 0.f, swe = 0.f;
    if (m > -INFINITY) {
        if (has0) {
            float e0 = expf(ss0 * sd - m);
            se += e0;
            swe += ss0 * e0;
        }
        for (int j = start + 64 + lane; j < end; j += 64) {
            float ss = score[csr_src[j]] + b;
            float e = expf(ss * sd - m);
            se += e;
            swe += ss * e;
        }
#pragma unroll
        for (int o = 32; o >= 1; o >>= 1) {
            se += __shfl_xor(se, o);
            swe += __shfl_xor(swe, o);
        }
    }
    float ns = (se > 0.f) ? (swe / se) : 0.f;
    if (lane == 0) nsf[wid] = sd + ns;
}

// ---------- fused graph-segment softmax: one block per graph ----------
__global__ __launch_bounds__(256) void graph_softmax_kernel(const float* __restrict__ nsf,
                                                            const int* __restrict__ batch,
                                                            float* __restrict__ out, int N) {
    int g = blockIdx.x;
    int tid = threadIdx.x;
    int lo = 0, hi = N;
    while (lo < hi) { int mid = (lo + hi) >> 1; if (batch[mid] < g) lo = mid + 1; else hi = mid; }
    int s0 = lo;
    hi = N;
    while (lo < hi) { int mid = (lo + hi) >> 1; if (batch[mid] < g + 1) lo = mid + 1; else hi = mid; }
    int s1 = lo;

    __shared__ float red[4];
    __shared__ float bval;
    float m = -INFINITY;
    for (int i = s0 + tid; i < s1; i += 256) m = fmaxf(m, nsf[i]);
#pragma unroll
    for (int o = 32; o >= 1; o >>= 1) m = fmaxf(m, __shfl_xor(m, o));
    if ((tid & 63) == 0) red[tid >> 6] = m;
    __syncthreads();
    if (tid == 0) bval = fmaxf(fmaxf(red[0], red[1]), fmaxf(red[2], red[3]));
    __syncthreads();
    float bmx = bval;
    float s = 0.f;
    for (int i = s0 + tid; i < s1; i += 256) {
        float e = expf(nsf[i] - bmx);
        out[i] = e;
        s += e;
    }
#pragma unroll
    for (int o = 32; o >= 1; o >>= 1) s += __shfl_xor(s, o);
    __syncthreads();
    if ((tid & 63) == 0) red[tid >> 6] = s;
    __syncthreads();
    if (tid == 0) bval = red[0] + red[1] + red[2] + red[3];
    __syncthreads();
    float inv = 1.f / bval;
    for (int i = s0 + tid; i < s1; i += 256) out[i] *= inv;
}

extern "C" void kernel_launch(void* const* d_in, const int* in_sizes, int n_in,
                              void* d_out, int out_size, void* d_ws, size_t ws_size,
                              hipStream_t stream) {
    const int N = N_NODES, E = N_EDGES;

    const float* x = (const float*)d_in[0];
    const int* ei = (const int*)d_in[1];
    const int* batch = (const int*)d_in[2];
    const float* W1a[3] = {(const float*)d_in[3], (const float*)d_in[7], (const float*)d_in[11]};
    const float* b1a[3] = {(const float*)d_in[4], (const float*)d_in[8], (const float*)d_in[12]};
    const float* W2a[3] = {(const float*)d_in[5], (const float*)d_in[9], (const float*)d_in[13]};
    const float* b2a[3] = {(const float*)d_in[6], (const float*)d_in[10], (const float*)d_in[14]};
    const float* Wm = (const float*)d_in[15];
    const float* bm = (const float*)d_in[16];
    float* out = (float*)d_out;

    const int* srcp = ei;
    const int* dstp = ei + E;

    // workspace layout (~59 MB; csrc_chunk aliases ubuf fully)
    float* ubuf = (float*)d_ws;                 // N*64 f32 (aliases csrc_chunk)
    int* csrc_chunk = (int*)ubuf;               // 2*E ints = 12.8MB
    __half* yA = (__half*)(ubuf + (size_t)N * 64);  // N*64 f16
    __half* yB = yA + (size_t)N * 64;               // N*64 f16
    float* score = (float*)(yB + (size_t)N * 64);   // N
    float* nsf = score + N;                     // N
    int* deg = (int*)(nsf + N);                 // N
    int* rowptr = deg + N;                      // N+1
    int* part = rowptr + N + 1;                 // 64
    int* csr_src = part + 64;                   // E
    unsigned short* locs = (unsigned short*)(csr_src + E);        // 2*CHUNKS*HNP1 u16
    unsigned short* base = locs + (size_t)2 * CHUNKS * HNP1;      // CHUNKS*N u16

    histsort_kernel<<<CHUNKS * 2, 1024, 0, stream>>>(srcp, dstp, csrc_chunk, locs);

    const int nbScan = (N + 1023) / 1024;  // 49
    base_scan1_kernel<<<nbScan, 1024, 0, stream>>>(locs, base, deg, part, N);
    scan3_kernel<<<nbScan, 1024, 0, stream>>>(deg, part, rowptr, N, nbScan);

    const int gfBlocks = 8 * ((N / 8 + 3) / 4);  // 12504
    gatherfill_kernel<<<gfBlocks, 256, 0, stream>>>(csrc_chunk, locs, base, rowptr, csr_src);

    const int gw = 4096;
    gemm0_kernel<<<1024, 256, 0, stream>>>(x, W1a[0], yA, N, gw);

    int aggBlocks = (N / 2 + 3) / 4;  // one wave per 2 nodes (half-wave each)

    agg_kernel<<<aggBlocks, 256, 0, stream>>>(yA, rowptr, csr_src, ubuf, N);
    mlpAB_kernel<0><<<1024, 256, 0, stream>>>(ubuf, b1a[0], W2a[0], b2a[0], W1a[1], Wm, yB, score, N, gw);

    agg_kernel<<<aggBlocks, 256, 0, stream>>>(yB, rowptr, csr_src, ubuf, N);
    mlpAB_kernel<1><<<1024, 256, 0, stream>>>(ubuf, b1a[1], W2a[1], b2a[1], W1a[2], Wm, yA, score, N, gw);

    agg_kernel<<<aggBlocks, 256, 0, stream>>>(yA, rowptr, csr_src, ubuf, N);
    mlpA2_kernel<<<1024, 256, 0, stream>>>(ubuf, b1a[2], W2a[2], b2a[2], Wm, score, N, gw);

    edge_softmax_kernel<<<(N + 3) / 4, 256, 0, stream>>>(score, rowptr, csr_src, bm, nsf, N);

    graph_softmax_kernel<<<N_GRAPH, 256, 0, stream>>>(nsf, batch, out, N);
}

// Round 17
// 320.263 us; speedup vs baseline: 1.1632x; 1.0017x over previous
//
#include <hip/hip_runtime.h>
#include <hip/hip_fp16.h>
#include <math.h>

#define N_NODES 50000
#define N_EDGES 1600000
#define N_GRAPH 500
#define CHUNKS 128
#define EPC (N_EDGES / CHUNKS)  // 12500 edges per chunk
#define NP1 (N_NODES + 1)
#define NIT ((EPC + 1023) / 1024)  // 13 edge-iterations per histsort thread
#define HALF_N (N_NODES / 2)       // 25000 nodes per half-range
#define HNP1 (HALF_N + 1)

// ---------- helpers ----------
__device__ __forceinline__ float rl(float v, int k) {
    return __int_as_float(__builtin_amdgcn_readlane(__float_as_int(v), k));
}
// accumulate 8 fp16 (uint4) into two float4
__device__ __forceinline__ void hacc16(float4& A, float4& B, uint4 w) {
    float2 f0 = __half22float2(*reinterpret_cast<__half2*>(&w.x));
    float2 f1 = __half22float2(*reinterpret_cast<__half2*>(&w.y));
    float2 f2 = __half22float2(*reinterpret_cast<__half2*>(&w.z));
    float2 f3 = __half22float2(*reinterpret_cast<__half2*>(&w.w));
    A.x += f0.x; A.y += f0.y; A.z += f1.x; A.w += f1.y;
    B.x += f2.x; B.y += f2.y; B.z += f3.x; B.w += f3.y;
}

// ---------- histsort (half-range split): block = (chunk c, half h). ----------
__global__ __launch_bounds__(1024) void histsort_kernel(const int* __restrict__ src,
                                                        const int* __restrict__ dst,
                                                        int* __restrict__ csrc_chunk,
                                                        unsigned short* __restrict__ locs) {
    __shared__ unsigned packed[HALF_N / 2];  // 50 KB
    __shared__ unsigned aux[1024];
    const int c = blockIdx.x >> 1;
    const int h = blockIdx.x & 1;
    const int lo = h * HALF_N;
    const int s0 = c * EPC;
    const int tid = threadIdx.x;

    for (int i = tid; i < HALF_N / 2; i += 1024) packed[i] = 0;
    __syncthreads();

    unsigned short lrv[NIT];
#pragma unroll
    for (int it = 0; it < NIT; it++) {
        int e = s0 + it * 1024 + tid;
        if (e < s0 + EPC) {
            int d = dst[e];
            int ld = d - lo;
            if (ld >= 0 && ld < HALF_N) {
                int sh = (ld & 1) * 16;
                unsigned old = atomicAdd(&packed[ld >> 1], 1u << sh);
                lrv[it] = (unsigned short)((old >> sh) & 0xffffu);
            }
        }
    }
    __syncthreads();

    const int W = 13;
    int w0 = tid * W;
    int w1 = min(w0 + W, HALF_N / 2);
    unsigned run = 0;
    for (int i = w0; i < w1; i++) {
        unsigned v = packed[i];
        unsigned plo = v & 0xffffu, phi = v >> 16;
        packed[i] = run | ((run + plo) << 16);
        run += plo + phi;
    }
    aux[tid] = run;
    __syncthreads();
    for (int off = 1; off < 1024; off <<= 1) {
        unsigned t = (tid >= off) ? aux[tid - off] : 0;
        __syncthreads();
        aux[tid] += t;
        __syncthreads();
    }
    unsigned b0 = (tid == 0) ? 0 : aux[tid - 1];
    if (b0) {
        unsigned addv = b0 | (b0 << 16);
        for (int i = w0; i < w1; i++) packed[i] += addv;
    }
    __syncthreads();
    unsigned total = aux[1023];

    int* outc = csrc_chunk + (size_t)(c * 2 + h) * EPC;
#pragma unroll
    for (int it = 0; it < NIT; it++) {
        int e = s0 + it * 1024 + tid;
        if (e < s0 + EPC) {
            int d = dst[e];
            int ld = d - lo;
            if (ld >= 0 && ld < HALF_N) {
                unsigned pw = packed[ld >> 1];
                unsigned loc = (ld & 1) ? (pw >> 16) : (pw & 0xffffu);
                outc[loc + lrv[it]] = src[e];
            }
        }
    }
    unsigned short* lc = locs + (size_t)(c * 2 + h) * HNP1;
    for (int ld = tid; ld <= HALF_N; ld += 1024) {
        unsigned short v;
        if (ld == HALF_N) {
            v = (unsigned short)total;
        } else {
            unsigned pw = packed[ld >> 1];
            v = (unsigned short)((ld & 1) ? (pw >> 16) : (pw & 0xffffu));
        }
        lc[ld] = v;
    }
}

// ---------- base + scan1 fused ----------
__global__ __launch_bounds__(1024) void base_scan1_kernel(const unsigned short* __restrict__ locs,
                                                          unsigned short* __restrict__ base,
                                                          int* __restrict__ deg,
                                                          int* __restrict__ part, int N) {
    int d = blockIdx.x * 1024 + threadIdx.x;
    int run = 0;
    if (d < N) {
        int h = (d >= HALF_N) ? 1 : 0;
        int ld = d - h * HALF_N;
#pragma unroll 8
        for (int c = 0; c < CHUNKS; c++) {
            const unsigned short* lc = locs + (size_t)(c * 2 + h) * HNP1;
            int l0 = lc[ld];
            int l1 = lc[ld + 1];
            base[(size_t)c * N + d] = (unsigned short)run;
            run += l1 - l0;
        }
        deg[d] = run;
    }
    int v = run;
#pragma unroll
    for (int o = 32; o >= 1; o >>= 1) v += __shfl_xor(v, o);
    __shared__ int red[16];
    if ((threadIdx.x & 63) == 0) red[threadIdx.x >> 6] = v;
    __syncthreads();
    if (threadIdx.x == 0) {
        int s = 0;
#pragma unroll
        for (int k = 0; k < 16; k++) s += red[k];
        part[blockIdx.x] = s;
    }
}

// ---------- scan3 with self-computed block offset ----------
__global__ __launch_bounds__(1024) void scan3_kernel(const int* __restrict__ deg,
                                                     const int* __restrict__ part,
                                                     int* __restrict__ rowptr, int N, int nb) {
    __shared__ int blockOff;
    __shared__ int wsum[16];
    int lane = threadIdx.x & 63;
    int w = threadIdx.x >> 6;
    if (threadIdx.x < 64) {
        int pv = (lane < nb && lane < (int)blockIdx.x) ? part[lane] : 0;
#pragma unroll
        for (int o = 32; o >= 1; o >>= 1) pv += __shfl_xor(pv, o);
        if (lane == 0) blockOff = pv;
    }
    int i = blockIdx.x * 1024 + threadIdx.x;
    int v = (i < N) ? deg[i] : 0;
    int inc = v;
#pragma unroll
    for (int o = 1; o < 64; o <<= 1) {
        int t = __shfl_up(inc, o);
        if (lane >= o) inc += t;
    }
    if (lane == 63) wsum[w] = inc;
    __syncthreads();
    if (threadIdx.x < 16) {
        int x = wsum[threadIdx.x];
        int xo = x;
#pragma unroll
        for (int o = 1; o < 16; o <<= 1) {
            int t = __shfl_up(x, o);
            if ((int)threadIdx.x >= o) x += t;
        }
        wsum[threadIdx.x] = x - xo;
    }
    __syncthreads();
    int b = blockOff + wsum[w];
    if (i < N) {
        rowptr[i] = b + inc - v;
        if (i == N - 1) rowptr[N] = b + inc;
    }
}

// ---------- gatherfill: one wave per node, lane covers 2 chunks ----------
__global__ __launch_bounds__(256) void gatherfill_kernel(const int* __restrict__ csrc_chunk,
                                                         const unsigned short* __restrict__ locs,
                                                         const unsigned short* __restrict__ base,
                                                         const int* __restrict__ rowptr,
                                                         int* __restrict__ csr_src) {
    const int perXcd = N_NODES / 8;  // 6250
    int xcd = blockIdx.x & 7;
    int idx = (blockIdx.x >> 3) * 4 + (threadIdx.x >> 6);
    if (idx >= perXcd) return;
    int wid = xcd * perXcd + idx;
    int lane = threadIdx.x & 63;
    int h = (wid >= HALF_N) ? 1 : 0;
    int ld = wid - h * HALF_N;
    int rp = rowptr[wid];
#pragma unroll
    for (int cc = 0; cc < 2; cc++) {
        int c = lane + cc * 64;
        const unsigned short* lc = locs + (size_t)(c * 2 + h) * HNP1;
        int l0 = lc[ld];
        int l1 = lc[ld + 1];
        int cnt = l1 - l0;
        int ob = rp + (int)base[(size_t)c * N_NODES + wid];
        const int* in = csrc_chunk + (size_t)(c * 2 + h) * EPC + l0;
        for (int i = 0; i < cnt; i++) csr_src[ob + i] = in[i];
    }
}

// ---------- gemm0: y0 = x @ W1_0, both K-halves in registers, fp16 store ----------
__global__ __launch_bounds__(256, 2) void gemm0_kernel(const float* __restrict__ x,
                                                       const float* __restrict__ W1,
                                                       __half* __restrict__ y0,
                                                       int N, int totalWaves) {
    int lane = threadIdx.x & 63;
    int wid = (blockIdx.x * 256 + threadIdx.x) >> 6;
    float wA[64], wB[64];
#pragma unroll
    for (int k = 0; k < 64; k++) wA[k] = W1[k * 64 + lane];
#pragma unroll
    for (int k = 0; k < 64; k++) wB[k] = W1[(64 + k) * 64 + lane];
    for (int node = wid; node < N; node += totalWaves) {
        float xa = x[(size_t)node * 128 + lane];
        float xb = x[(size_t)node * 128 + 64 + lane];
        float a0 = 0.f, a1 = 0.f, a2 = 0.f, a3 = 0.f;
#pragma unroll
        for (int k = 0; k < 64; k += 4) {
            a0 = fmaf(rl(xa, k + 0), wA[k + 0], a0);
            a1 = fmaf(rl(xa, k + 1), wA[k + 1], a1);
            a2 = fmaf(rl(xa, k + 2), wA[k + 2], a2);
            a3 = fmaf(rl(xa, k + 3), wA[k + 3], a3);
        }
#pragma unroll
        for (int k = 0; k < 64; k += 4) {
            a0 = fmaf(rl(xb, k + 0), wB[k + 0], a0);
            a1 = fmaf(rl(xb, k + 1), wB[k + 1], a1);
            a2 = fmaf(rl(xb, k + 2), wB[k + 2], a2);
            a3 = fmaf(rl(xb, k + 3), wB[k + 3], a3);
        }
        y0[(size_t)node * 64 + lane] = __float2half((a0 + a1) + (a2 + a3));
    }
}

// ---------- aggregation: half-wave per node, 4 edge slots x 8 feature lanes ----------
__global__ __launch_bounds__(256) void agg_kernel(const __half* __restrict__ yh,
                                                  const int* __restrict__ rowptr,
                                                  const int* __restrict__ csr_src,
                                                  float* __restrict__ u, int N) {
    int wv = (blockIdx.x * 256 + threadIdx.x) >> 6;
    int half = (threadIdx.x >> 5) & 1;
    int node = wv * 2 + half;
    if (node >= N) return;
    int lane = threadIdx.x & 31;  // lane within half-wave
    int q = lane >> 3;            // edge slot 0..3
    int r = lane & 7;             // feature oct 0..7 (16B)
    int start = rowptr[node];
    int end = rowptr[node + 1];
    float4 A = make_float4(0.f, 0.f, 0.f, 0.f);
    float4 B = make_float4(0.f, 0.f, 0.f, 0.f);
    int j = start;
    for (; j + 32 <= end; j += 32) {
        int s0 = csr_src[j + q];
        int s1 = csr_src[j + 4 + q];
        int s2 = csr_src[j + 8 + q];
        int s3 = csr_src[j + 12 + q];
        int s4 = csr_src[j + 16 + q];
        int s5 = csr_src[j + 20 + q];
        int s6 = csr_src[j + 24 + q];
        int s7 = csr_src[j + 28 + q];
        uint4 w0 = *(const uint4*)(yh + (size_t)s0 * 64 + r * 8);
        uint4 w1 = *(const uint4*)(yh + (size_t)s1 * 64 + r * 8);
        uint4 w2 = *(const uint4*)(yh + (size_t)s2 * 64 + r * 8);
        uint4 w3 = *(const uint4*)(yh + (size_t)s3 * 64 + r * 8);
        uint4 w4 = *(const uint4*)(yh + (size_t)s4 * 64 + r * 8);
        uint4 w5 = *(const uint4*)(yh + (size_t)s5 * 64 + r * 8);
        uint4 w6 = *(const uint4*)(yh + (size_t)s6 * 64 + r * 8);
        uint4 w7 = *(const uint4*)(yh + (size_t)s7 * 64 + r * 8);
        hacc16(A, B, w0); hacc16(A, B, w1); hacc16(A, B, w2); hacc16(A, B, w3);
        hacc16(A, B, w4); hacc16(A, B, w5); hacc16(A, B, w6); hacc16(A, B, w7);
    }
#pragma unroll
    for (int m = 0; m < 8; m++) {
        int e = j + 4 * m + q;
        if (e < end) {
            int s = csr_src[e];
            uint4 w = *(const uint4*)(yh + (size_t)s * 64 + r * 8);
            hacc16(A, B, w);
        }
    }
#pragma unroll
    for (int o = 8; o <= 16; o <<= 1) {
        A.x += __shfl_xor(A.x, o); A.y += __shfl_xor(A.y, o);
        A.z += __shfl_xor(A.z, o); A.w += __shfl_xor(A.w, o);
        B.x += __shfl_xor(B.x, o); B.y += __shfl_xor(B.y, o);
        B.z += __shfl_xor(B.z, o); B.w += __shfl_xor(B.w, o);
    }
    if (lane < 8) {
        uint4 w = *(const uint4*)(yh + (size_t)node * 64 + r * 8);
        hacc16(A, B, w);
        *(float4*)(u + (size_t)node * 64 + r * 8) = A;
        *(float4*)(u + (size_t)node * 64 + r * 8 + 4) = B;
    }
}

// ---------- fused mlpAB (layers 0,1): fp32 u in, fp16 ynext out ----------
template <int LAYER>
__global__ __launch_bounds__(256, 2) void mlpAB_kernel(const float* __restrict__ u,
                                                       const float* __restrict__ b1,
                                                       const float* __restrict__ W2,
                                                       const float* __restrict__ b2,
                                                       const float* __restrict__ W1n,
                                                       const float* __restrict__ Wm,
                                                       __half* __restrict__ ynext,
                                                       float* __restrict__ score,
                                                       int N, int totalWaves) {
    int lane = threadIdx.x & 63;
    int wid = (blockIdx.x * 256 + threadIdx.x) >> 6;
    float w2[64], w1[64];
#pragma unroll
    for (int k = 0; k < 64; k++) w2[k] = W2[k * 64 + lane];
#pragma unroll
    for (int k = 0; k < 64; k++) w1[k] = W1n[k * 64 + lane];
    float bb1 = b1[lane], bb2 = b2[lane], wm = Wm[LAYER * 64 + lane];

    int node = wid;
    float uin = (node < N) ? u[(size_t)node * 64 + lane] : 0.f;
    for (; node < N; node += totalWaves) {
        int nn = node + totalWaves;
        float unext = (nn < N) ? u[(size_t)nn * 64 + lane] : 0.f;
        float t = fmaxf(uin + bb1, 0.f);
        float a0 = 0.f, a1 = 0.f, a2 = 0.f, a3 = 0.f;
#pragma unroll
        for (int k = 0; k < 64; k += 4) {
            a0 = fmaf(rl(t, k + 0), w2[k + 0], a0);
            a1 = fmaf(rl(t, k + 1), w2[k + 1], a1);
            a2 = fmaf(rl(t, k + 2), w2[k + 2], a2);
            a3 = fmaf(rl(t, k + 3), w2[k + 3], a3);
        }
        float h = fmaxf(bb2 + ((a0 + a1) + (a2 + a3)), 0.f);
        float p = h * wm;
#pragma unroll
        for (int o = 32; o >= 1; o >>= 1) p += __shfl_xor(p, o);
        if (lane == 0) {
            if (LAYER == 0) score[node] = p;
            else score[node] += p;
        }
        float y0 = 0.f, y1 = 0.f, y2 = 0.f, y3 = 0.f;
#pragma unroll
        for (int k = 0; k < 64; k += 4) {
            y0 = fmaf(rl(h, k + 0), w1[k + 0], y0);
            y1 = fmaf(rl(h, k + 1), w1[k + 1], y1);
            y2 = fmaf(rl(h, k + 2), w1[k + 2], y2);
            y3 = fmaf(rl(h, k + 3), w1[k + 3], y3);
        }
        ynext[(size_t)node * 64 + lane] = __float2half((y0 + y1) + (y2 + y3));
        uin = unext;
    }
}

// ---------- mlpA2 (layer 2) ----------
__global__ __launch_bounds__(256, 2) void mlpA2_kernel(const float* __restrict__ u,
                                                       const float* __restrict__ b1,
                                                       const float* __restrict__ W2,
                                                       const float* __restrict__ b2,
                                                       const float* __restrict__ Wm,
                                                       float* __restrict__ score,
                                                       int N, int totalWaves) {
    int lane = threadIdx.x & 63;
    int wid = (blockIdx.x * 256 + threadIdx.x) >> 6;
    float w2[64];
#pragma unroll
    for (int k = 0; k < 64; k++) w2[k] = W2[k * 64 + lane];
    float bb1 = b1[lane], bb2 = b2[lane], wm = Wm[2 * 64 + lane];

    int node = wid;
    float uin = (node < N) ? u[(size_t)node * 64 + lane] : 0.f;
    for (; node < N; node += totalWaves) {
        int nn = node + totalWaves;
        float unext = (nn < N) ? u[(size_t)nn * 64 + lane] : 0.f;
        float t = fmaxf(uin + bb1, 0.f);
        float a0 = 0.f, a1 = 0.f, a2 = 0.f, a3 = 0.f;
#pragma unroll
        for (int k = 0; k < 64; k += 4) {
            a0 = fmaf(rl(t, k + 0), w2[k + 0], a0);
            a1 = fmaf(rl(t, k + 1), w2[k + 1], a1);
            a2 = fmaf(rl(t, k + 2), w2[k + 2], a2);
            a3 = fmaf(rl(t, k + 3), w2[k + 3], a3);
        }
        float h = bb2 + ((a0 + a1) + (a2 + a3));
        float p = h * wm;
#pragma unroll
        for (int o = 32; o >= 1; o >>= 1) p += __shfl_xor(p, o);
        if (lane == 0) score[node] += p;
        uin = unext;
    }
}

// ---------- edge softmax + new_score ----------
__global__ __launch_bounds__(256) void edge_softmax_kernel(const float* __restrict__ score,
                                                           const int* __restrict__ rowptr,
                                                           const int* __restrict__ csr_src,
                                                           const float* __restrict__ bm,
                                                           float* __restrict__ nsf, int N) {
    int wid = (blockIdx.x * blockDim.x + threadIdx.x) >> 6;
    int lane = threadIdx.x & 63;
    if (wid >= N) return;
    float b = bm[0];
    float sd = score[wid] + b;
    int start = rowptr[wid];
    int end = rowptr[wid + 1];
    bool has0 = (start + lane < end);
    float ss0 = 0.f;
    float m = -INFINITY;
    if (has0) {
        ss0 = score[csr_src[start + lane]] + b;
        m = ss0 * sd;
    }
    for (int j = start + 64 + lane; j < end; j += 64) {
        float ss = score[csr_src[j]] + b;
        m = fmaxf(m, ss * sd);
    }
#pragma unroll
    for (int o = 32; o >= 1; o >>= 1) m = fmaxf(m, __shfl_xor(m, o));
    float se = 0.f, swe = 0.f;
    if (m > -INFINITY) {
        if (has0) {
            float e0 = expf(ss0 * sd - m);
            se += e0;
            swe += ss0 * e0;
        }
        for (int j = start + 64 + lane; j < end; j += 64) {
            float ss = score[csr_src[j]] + b;
            float e = expf(ss * sd - m);
            se += e;
            swe += ss * e;
        }
#pragma unroll
        for (int o = 32; o >= 1; o >>= 1) {
            se += __shfl_xor(se, o);
            swe += __shfl_xor(swe, o);
        }
    }
    float ns = (se > 0.f) ? (swe / se) : 0.f;
    if (lane == 0) nsf[wid] = sd + ns;
}

// ---------- fused graph-segment softmax: one block per graph ----------
__global__ __launch_bounds__(256) void graph_softmax_kernel(const float* __restrict__ nsf,
                                                            const int* __restrict__ batch,
                                                            float* __restrict__ out, int N) {
    int g = blockIdx.x;
    int tid = threadIdx.x;
    int lo = 0, hi = N;
    while (lo < hi) { int mid = (lo + hi) >> 1; if (batch[mid] < g) lo = mid + 1; else hi = mid; }
    int s0 = lo;
    hi = N;
    while (lo < hi) { int mid = (lo + hi) >> 1; if (batch[mid] < g + 1) lo = mid + 1; else hi = mid; }
    int s1 = lo;

    __shared__ float red[4];
    __shared__ float bval;
    float m = -INFINITY;
    for (int i = s0 + tid; i < s1; i += 256) m = fmaxf(m, nsf[i]);
#pragma unroll
    for (int o = 32; o >= 1; o >>= 1) m = fmaxf(m, __shfl_xor(m, o));
    if ((tid & 63) == 0) red[tid >> 6] = m;
    __syncthreads();
    if (tid == 0) bval = fmaxf(fmaxf(red[0], red[1]), fmaxf(red[2], red[3]));
    __syncthreads();
    float bmx = bval;
    float s = 0.f;
    for (int i = s0 + tid; i < s1; i += 256) {
        float e = expf(nsf[i] - bmx);
        out[i] = e;
        s += e;
    }
#pragma unroll
    for (int o = 32; o >= 1; o >>= 1) s += __shfl_xor(s, o);
    __syncthreads();
    if ((tid & 63) == 0) red[tid >> 6] = s;
    __syncthreads();
    if (tid == 0) bval = red[0] + red[1] + red[2] + red[3];
    __syncthreads();
    float inv = 1.f / bval;
    for (int i = s0 + tid; i < s1; i += 256) out[i] *= inv;
}

extern "C" void kernel_launch(void* const* d_in, const int* in_sizes, int n_in,
                              void* d_out, int out_size, void* d_ws, size_t ws_size,
                              hipStream_t stream) {
    const int N = N_NODES, E = N_EDGES;

    const float* x = (const float*)d_in[0];
    const int* ei = (const int*)d_in[1];
    const int* batch = (const int*)d_in[2];
    const float* W1a[3] = {(const float*)d_in[3], (const float*)d_in[7], (const float*)d_in[11]};
    const float* b1a[3] = {(const float*)d_in[4], (const float*)d_in[8], (const float*)d_in[12]};
    const float* W2a[3] = {(const float*)d_in[5], (const float*)d_in[9], (const float*)d_in[13]};
    const float* b2a[3] = {(const float*)d_in[6], (const float*)d_in[10], (const float*)d_in[14]};
    const float* Wm = (const float*)d_in[15];
    const float* bm = (const float*)d_in[16];
    float* out = (float*)d_out;

    const int* srcp = ei;
    const int* dstp = ei + E;

    // workspace layout (~59 MB; csrc_chunk aliases ubuf fully)
    float* ubuf = (float*)d_ws;                 // N*64 f32 (aliases csrc_chunk)
    int* csrc_chunk = (int*)ubuf;               // 2*E ints = 12.8MB
    __half* yA = (__half*)(ubuf + (size_t)N * 64);  // N*64 f16
    __half* yB = yA + (size_t)N * 64;               // N*64 f16
    float* score = (float*)(yB + (size_t)N * 64);   // N
    float* nsf = score + N;                     // N
    int* deg = (int*)(nsf + N);                 // N
    int* rowptr = deg + N;                      // N+1
    int* part = rowptr + N + 1;                 // 64
    int* csr_src = part + 64;                   // E
    unsigned short* locs = (unsigned short*)(csr_src + E);        // 2*CHUNKS*HNP1 u16
    unsigned short* base = locs + (size_t)2 * CHUNKS * HNP1;      // CHUNKS*N u16

    histsort_kernel<<<CHUNKS * 2, 1024, 0, stream>>>(srcp, dstp, csrc_chunk, locs);

    const int nbScan = (N + 1023) / 1024;  // 49
    base_scan1_kernel<<<nbScan, 1024, 0, stream>>>(locs, base, deg, part, N);
    scan3_kernel<<<nbScan, 1024, 0, stream>>>(deg, part, rowptr, N, nbScan);

    const int gfBlocks = 8 * ((N / 8 + 3) / 4);  // 12504
    gatherfill_kernel<<<gfBlocks, 256, 0, stream>>>(csrc_chunk, locs, base, rowptr, csr_src);

    const int gw = 4096;
    gemm0_kernel<<<1024, 256, 0, stream>>>(x, W1a[0], yA, N, gw);

    int aggBlocks = (N / 2 + 3) / 4;  // one wave per 2 nodes (half-wave each)

    agg_kernel<<<aggBlocks, 256, 0, stream>>>(yA, rowptr, csr_src, ubuf, N);
    mlpAB_kernel<0><<<1024, 256, 0, stream>>>(ubuf, b1a[0], W2a[0], b2a[0], W1a[1], Wm, yB, score, N, gw);

    agg_kernel<<<aggBlocks, 256, 0, stream>>>(yB, rowptr, csr_src, ubuf, N);
    mlpAB_kernel<1><<<1024, 256, 0, stream>>>(ubuf, b1a[1], W2a[1], b2a[1], W1a[2], Wm, yA, score, N, gw);

    agg_kernel<<<aggBlocks, 256, 0, stream>>>(yA, rowptr, csr_src, ubuf, N);
    mlpA2_kernel<<<1024, 256, 0, stream>>>(ubuf, b1a[2], W2a[2], b2a[2], Wm, score, N, gw);

    edge_softmax_kernel<<<(N + 3) / 4, 256, 0, stream>>>(score, rowptr, csr_src, bm, nsf, N);

    graph_softmax_kernel<<<N_GRAPH, 256, 0, stream>>>(nsf, batch, out, N);
}